// Round 4
// baseline (1533.773 us; speedup 1.0000x reference)
//
#include <hip/hip_runtime.h>
#include <math.h>

// Problem constants
#define B_    512
#define W_    4
#define KD_   64
#define NC_   32
#define D_    256
#define NN_   16
#define NH_   8
#define AD_   32
#define HOPS_ 4
#define DH_   32
#define DFF_  1024
#define P_    2560
#define BW_   2048   // B*W
#define MAXT2_ 176   // worst-case 16-row M-tiles: P/16 + (NN-1) = 175 -> 176 (%8==0)
#define PS_   (P_ + 16)  // padded row stride for partial buffers

#define INV_SQRT_DH 0.17677669529663687f  // 1/sqrt(32)

// ---------------- block-wide sum over 256 threads ----------------
__device__ __forceinline__ float block_sum256(float v, float* red) {
#pragma unroll
  for (int off = 32; off > 0; off >>= 1) v += __shfl_xor(v, off, 64);
  int wid = threadIdx.x >> 6;
  if ((threadIdx.x & 63) == 0) red[wid] = v;
  __syncthreads();
  float s = red[0] + red[1] + red[2] + red[3];
  __syncthreads();
  return s;
}

__device__ __forceinline__ float gelu_tanh(float v) {
  float u = 0.7978845608028654f * (v + 0.044715f * v * v * v);
  return 0.5f * v * (1.0f + tanhf(u));
}

// ---------------- encode writers + queries -> h, node ----------------
__global__ __launch_bounds__(256) void encode_kernel(
    const float* __restrict__ query_keys, const float* __restrict__ writer_keys,
    const float* __restrict__ kpw, const float* __restrict__ kpb,
    const float* __restrict__ ce, const float* __restrict__ re,
    const float* __restrict__ sne, const float* __restrict__ ilg,
    const float* __restrict__ ilb, const int* __restrict__ qsn,
    const int* __restrict__ wl, const int* __restrict__ wsn,
    float* __restrict__ h, int* __restrict__ node) {
  int p = blockIdx.x, t = threadIdx.x;
  __shared__ float fk[KD_];
  __shared__ float red[4];
  const float* key;
  int lab = -1, sn, role;
  if (p < BW_) { key = writer_keys + (size_t)p * KD_; lab = wl[p]; sn = wsn[p]; role = 0; }
  else { int b = p - BW_; key = query_keys + (size_t)b * KD_; sn = qsn[b]; role = 1; }
  if (t < KD_) fk[t] = key[t];
  __syncthreads();

  float acc = kpb[t] + sne[sn * D_ + t] + re[role * D_ + t];
  if (lab >= 0) acc += ce[lab * D_ + t];
#pragma unroll 8
  for (int i = 0; i < KD_; i++) acc += fk[i] * kpw[i * D_ + t];

  float mean = block_sum256(acc, red) * (1.0f / D_);
  float d = acc - mean;
  float var = block_sum256(d * d, red) * (1.0f / D_);
  float xn = d * (1.0f / sqrtf(var + 1e-5f));

  float sw = 0.0f;
  if (t < KD_) sw = fk[t];
  else if (lab >= 0 && t < KD_ + NC_) sw = (t - KD_ == lab) ? 1.0f : 0.0f;

  h[(size_t)p * D_ + t] = xn * ilg[t] + ilb[t] + sw;
  if (t == 0) node[p] = sn;
}

// ---------------- group packets by node + 16-row tile worklist + inverse map -
__global__ __launch_bounds__(256) void sort_kernel(const int* __restrict__ node,
                                                   int* __restrict__ order,
                                                   int* __restrict__ invord,
                                                   int* __restrict__ offs,
                                                   int* __restrict__ cnts,
                                                   int* __restrict__ tnode,
                                                   int* __restrict__ tstart,
                                                   int* __restrict__ tend,
                                                   int* __restrict__ ntiles) {
  __shared__ int c[NN_], o[NN_], cur[NN_];
  int t = threadIdx.x;
  if (t < NN_) c[t] = 0;
  __syncthreads();
  for (int p = t; p < P_; p += 256) atomicAdd(&c[node[p]], 1);
  __syncthreads();
  if (t == 0) {
    int s = 0;
    for (int n = 0; n < NN_; n++) { o[n] = s; cur[n] = s; s += c[n]; }
    int idx = 0;
    for (int n = 0; n < NN_; n++) {
      int e = o[n] + c[n];
      for (int m0 = o[n]; m0 < e; m0 += 16) {
        tnode[idx] = n; tstart[idx] = m0; tend[idx] = e; idx++;
      }
    }
    ntiles[0] = idx;
  }
  __syncthreads();
  if (t < NN_) { cnts[t] = c[t]; offs[t] = o[t]; }
  for (int p = t; p < P_; p += 256) {
    int r = atomicAdd(&cur[node[p]], 1);
    order[r] = p;
    invord[p] = r;
  }
}

// ---------------- LN with per-node affine, wave-per-row, SORTED out ---------
__global__ __launch_bounds__(256) void ln_affine(const float* __restrict__ h,
                                                 const float* __restrict__ g,
                                                 const float* __restrict__ b,
                                                 const int* __restrict__ node,
                                                 const int* __restrict__ order,
                                                 float* __restrict__ x) {
  int sp = blockIdx.x * 4 + (threadIdx.x >> 6);
  int lane = threadIdx.x & 63;
  int p = order[sp];
  int n = node[p];
  float4 v = *(const float4*)&h[(size_t)p * D_ + lane * 4];
  float s = v.x + v.y + v.z + v.w;
#pragma unroll
  for (int off = 32; off > 0; off >>= 1) s += __shfl_xor(s, off, 64);
  float mean = s * (1.0f / D_);
  float4 d = make_float4(v.x - mean, v.y - mean, v.z - mean, v.w - mean);
  float vr = d.x * d.x + d.y * d.y + d.z * d.z + d.w * d.w;
#pragma unroll
  for (int off = 32; off > 0; off >>= 1) vr += __shfl_xor(vr, off, 64);
  float inv = 1.0f / sqrtf(vr * (1.0f / D_) + 1e-5f);
  float4 gg = *(const float4*)&g[n * D_ + lane * 4];
  float4 bb = *(const float4*)&b[n * D_ + lane * 4];
  float4 o;
  o.x = d.x * inv * gg.x + bb.x;
  o.y = d.y * inv * gg.y + bb.y;
  o.z = d.z * inv * gg.z + bb.z;
  o.w = d.w * inv * gg.w + bb.w;
  *(float4*)&x[(size_t)sp * D_ + lane * 4] = o;
}

// ---------------- grouped linear v5: 2 row-groups x 2 col-halves ------------
// Block = 256 threads = 4 waves. Tile = RT rows x 256 cols. Wave wv:
// rh=wv>>1 -> rows [s0+rh*RPW, +RPW), ch=wv&1 -> cols [jb+ch*128+2*lane, +2).
// W staged to LDS via global_load_lds (16B/lane, 1KB per k-row), double-
// buffered KC=16 (32 KB total -> up to 5 blocks/CU). x rows are WAVE-UNIFORM
// register loads (broadcast), float4 = 4 k-steps, ping-ponged.
// Per wave per k: 1 ds_read_b64 (~8 LDS-cyc) feeds RPW*2 FMAs (RT=16: 32
// SIMD-cyc) -> VALU/LDS balanced, vs glin4's LDS-bound 1:b128/16FMA.
// KSPLIT: z=0 main (bias/act/resid); z>=1 raw partial -> pbuf part z-1
// (sorted space, [3][PS_][DOUT]). XMODE 1: x[p] + sum of 3 pbuf parts at
// invord[p] (dense packet space, PER_NODE=0 only).
template <int DIN, int DOUT, int RT, int ACT, int RESID, int PER_NODE, int KSPLIT,
          int XMODE>
__global__ __launch_bounds__(256) void glin5(const float* __restrict__ x,
                                             const float* __restrict__ W,
                                             const float* __restrict__ bias,
                                             float* __restrict__ out,
                                             float* __restrict__ pbuf,
                                             const float* __restrict__ xaux,
                                             const int* __restrict__ order,
                                             const int* __restrict__ invord,
                                             const int* __restrict__ tnode,
                                             const int* __restrict__ tstart,
                                             const int* __restrict__ tend,
                                             const int* __restrict__ ntiles) {
  constexpr int KC = 16;            // k-rows per LDS chunk
  constexpr int KLEN = DIN / KSPLIT;
  constexpr int NCH = KLEN / KC;
  constexpr int RPW = RT / 2;       // rows per wave (8 or 4)

  __shared__ float ws[2][KC][256];  // 32 KB

  // bijective XCD swizzle (gridDim.x % 8 == 0 by construction)
  int gx = gridDim.x;
  int bid = blockIdx.x;
  int ti = (bid & 7) * (gx >> 3) + (bid >> 3);

  int n, s0, rows;
  if (PER_NODE) {
    int tt = (RT == 16) ? ti : (ti >> 1);
    if (tt >= ntiles[0]) return;
    n = tnode[tt];
    s0 = tstart[tt] + ((RT == 8) ? (ti & 1) * 8 : 0);
    int e = tend[tt];
    rows = e - s0;
    if (rows <= 0) return;  // empty second half-tile of a short group
    if (rows > RT) rows = RT;
  } else {
    n = 0;
    s0 = ti * RT;
    rows = RT;
  }
  int jb = blockIdx.y * 256;
  int kz = (KSPLIT > 1) ? blockIdx.z : 0;
  int k0 = kz * KLEN;

  int tid = threadIdx.x;
  int wv = __builtin_amdgcn_readfirstlane((int)(tid >> 6));  // 0..3, uniform
  int lane = tid & 63;
  int rh = wv >> 1;        // row half (uniform)
  int ch = wv & 1;         // col half (uniform)
  int jc2 = ch * 128 + lane * 2;  // my 2 cols within the 256-col panel

  const float* Wn = W + (size_t)n * DIN * DOUT + jb;

  // ---- W staging: wave wv covers k-rows [wv*4, wv*4+4) of the chunk ----
  auto wstage = [&](int buf, int kc) {
#pragma unroll
    for (int i = 0; i < KC / 4; i++) {
      int kr = wv * (KC / 4) + i;
      const float* g = Wn + (size_t)(k0 + kc + kr) * DOUT + (lane << 2);
      __builtin_amdgcn_global_load_lds(
          (const __attribute__((address_space(1))) unsigned int*)g,
          (__attribute__((address_space(3))) unsigned int*)&ws[buf][kr][0],
          16, 0, 0);
    }
  };

  // ---- x row bases (RPW wave-local rows; wave-uniform broadcast loads) ----
  int rbase = s0 + rh * RPW;  // buffers padded +16 rows -> tail reads in-bounds
  const float* xb = x + (size_t)rbase * DIN + k0;
  int inv[RPW];
  if (XMODE == 1) {
#pragma unroll
    for (int r = 0; r < RPW; r++) inv[r] = invord[rbase + r];
  }

  float4 xA[RPW], xB[RPW];
  auto xfetch = [&](int kk, float4 (&dst)[RPW]) {
#pragma unroll
    for (int r = 0; r < RPW; r++) {
      dst[r] = *(const float4*)(xb + (size_t)r * DIN + kk);
      if (XMODE == 1) {
#pragma unroll
        for (int q = 0; q < 3; q++) {
          float4 a = *(const float4*)(xaux + ((size_t)q * PS_ + inv[r]) * DIN + kk);
          dst[r].x += a.x; dst[r].y += a.y; dst[r].z += a.z; dst[r].w += a.w;
        }
      }
    }
  };

  float2 acc[RPW];
#pragma unroll
  for (int r = 0; r < RPW; r++) acc[r] = make_float2(0.f, 0.f);

  auto compute4 = [&](int buf, int kb, float4 (&X)[RPW]) {
#pragma unroll
    for (int kq = 0; kq < 4; kq++) {
      float2 w2 = *(const float2*)&ws[buf][kb + kq][jc2];
#pragma unroll
      for (int r = 0; r < RPW; r++) {
        float f = (kq == 0) ? X[r].x : (kq == 1) ? X[r].y : (kq == 2) ? X[r].z : X[r].w;
        acc[r].x += f * w2.x;
        acc[r].y += f * w2.y;
      }
    }
  };

  wstage(0, 0);
  xfetch(0, xA);
  __syncthreads();  // drains vmcnt (incl. global_load_lds) before first use

  for (int c = 0; c < NCH; c++) {
    int cur = c & 1;
    if (c + 1 < NCH) wstage(cur ^ 1, (c + 1) * KC);
    int gk = c * KC;
#pragma unroll
    for (int kb = 0; kb < KC; kb += 8) {
      if (gk + kb + 4 < KLEN) xfetch(gk + kb + 4, xB);
      compute4(cur, kb, xA);
      if (gk + kb + 8 < KLEN) xfetch(gk + kb + 8, xA);
      compute4(cur, kb + 4, xB);
    }
    __syncthreads();
  }

  // ---- epilogue ----
  int jcol = jb + jc2;
  bool main_part = (KSPLIT == 1) || (kz == 0);
  float2 bv = make_float2(0.f, 0.f);
  if (main_part) bv = *(const float2*)&bias[(size_t)n * DOUT + jcol];

#pragma unroll
  for (int r = 0; r < RPW; r++) {
    int lr = rh * RPW + r;
    if (PER_NODE && lr >= rows) continue;
    float2 av = acc[r];
    if (main_part) {
      float2 v = make_float2(av.x + bv.x, av.y + bv.y);
      if (ACT == 1) { v.x = gelu_tanh(v.x); v.y = gelu_tanh(v.y); }
      if (RESID) {
        int pp = PER_NODE ? order[s0 + lr] : (s0 + lr);
        float* op = out + (size_t)pp * DOUT + jcol;
        float2 old = *(const float2*)op;
        *(float2*)op = make_float2(v.x + old.x, v.y + old.y);
      } else {
        *(float2*)(out + (size_t)(s0 + lr) * DOUT + jcol) = v;
      }
    } else {
      // raw partial, sorted space, part (kz-1)
      float* op = pbuf + ((size_t)(kz - 1) * PS_ + (s0 + lr)) * DOUT + jcol;
      *(float2*)op = av;
    }
  }
}

// ---------------- same-node attention, flash-style, sorted qkv/ao ----------
#define ATS 36  // padded LDS stride (floats): multiple of 4 (float4 align), !=32 (banks)
__global__ __launch_bounds__(256) void attn_kernel(const float* __restrict__ qkv,
                                                   const int* __restrict__ node,
                                                   const int* __restrict__ order,
                                                   const int* __restrict__ offs,
                                                   const int* __restrict__ cnts,
                                                   float* __restrict__ ao) {
  __shared__ float qs[32 * ATS];   // Q row-major [r][d]
  __shared__ float kts[32 * ATS];  // K transposed [d][j]
  __shared__ float vs[32 * ATS];   // V row-major [j][d]
  __shared__ float ps[32 * ATS];   // P row-major [r][j] (wave-coherent use)
  __shared__ int glo[32], ghi[32];

  int t = threadIdx.x;
  int r = t >> 3;          // my q-row (and my staging key-row)
  int j4 = (t & 7) * 4;    // my 4 score-cols == my 4 output dims
  int r0 = blockIdx.x * 32;
  int hd = blockIdx.y;

  if (t < 32) {
    int n = node[order[r0 + t]];
    glo[t] = offs[n];
    ghi[t] = offs[n] + cnts[n];
  }
  __syncthreads();

  {  // Q tile: sorted row r0+r, coalesced
    const float* qp = &qkv[(size_t)(r0 + r) * 768 + hd * 32 + j4];
    float4 q4 = *(const float4*)qp;
    q4.x *= INV_SQRT_DH; q4.y *= INV_SQRT_DH; q4.z *= INV_SQRT_DH; q4.w *= INV_SQRT_DH;
    *(float4*)&qs[r * ATS + j4] = q4;
  }

  int lo = glo[0];
  int hi = ghi[31];
  int myglo = glo[r], myghi = ghi[r];

  float4 o4 = {0.f, 0.f, 0.f, 0.f};
  float mrow = -1e30f, lrow = 0.f;

  for (int kt = lo; kt < hi; kt += 32) {
    int sj = kt + r;
    float4 k4 = {0.f, 0.f, 0.f, 0.f}, v4 = {0.f, 0.f, 0.f, 0.f};
    if (sj < hi) {
      const float* kp = &qkv[(size_t)sj * 768 + 256 + hd * 32 + j4];
      k4 = *(const float4*)kp;
      v4 = *(const float4*)(kp + 256);
    }
    __syncthreads();
    kts[(j4 + 0) * ATS + r] = k4.x;
    kts[(j4 + 1) * ATS + r] = k4.y;
    kts[(j4 + 2) * ATS + r] = k4.z;
    kts[(j4 + 3) * ATS + r] = k4.w;
    *(float4*)&vs[r * ATS + j4] = v4;
    __syncthreads();

    float s0 = 0.f, s1 = 0.f, s2 = 0.f, s3 = 0.f;
#pragma unroll 8
    for (int d = 0; d < 32; d++) {
      float qv = qs[r * ATS + d];
      float4 kv = *(const float4*)&kts[d * ATS + j4];
      s0 += qv * kv.x; s1 += qv * kv.y; s2 += qv * kv.z; s3 += qv * kv.w;
    }
    int c0 = kt + j4;
    if (c0 + 0 < myglo || c0 + 0 >= myghi) s0 = -1e30f;
    if (c0 + 1 < myglo || c0 + 1 >= myghi) s1 = -1e30f;
    if (c0 + 2 < myglo || c0 + 2 >= myghi) s2 = -1e30f;
    if (c0 + 3 < myglo || c0 + 3 >= myghi) s3 = -1e30f;

    float mx = fmaxf(fmaxf(s0, s1), fmaxf(s2, s3));
#pragma unroll
    for (int off = 4; off > 0; off >>= 1) mx = fmaxf(mx, __shfl_xor(mx, off, 8));
    float mnew = fmaxf(mrow, mx);
    float alpha = __expf(mrow - mnew);
    float p0 = __expf(s0 - mnew), p1 = __expf(s1 - mnew);
    float p2 = __expf(s2 - mnew), p3 = __expf(s3 - mnew);
    float ls = p0 + p1 + p2 + p3;
#pragma unroll
    for (int off = 4; off > 0; off >>= 1) ls += __shfl_xor(ls, off, 8);
    lrow = lrow * alpha + ls;
    mrow = mnew;
    o4.x *= alpha; o4.y *= alpha; o4.z *= alpha; o4.w *= alpha;

    *(float4*)&ps[r * ATS + j4] = make_float4(p0, p1, p2, p3);
#pragma unroll 8
    for (int j = 0; j < 32; j++) {
      float pj = ps[r * ATS + j];
      float4 vv = *(const float4*)&vs[j * ATS + j4];
      o4.x += pj * vv.x; o4.y += pj * vv.y; o4.z += pj * vv.z; o4.w += pj * vv.w;
    }
  }

  float inv = 1.f / lrow;
  o4.x *= inv; o4.y *= inv; o4.z *= inv; o4.w *= inv;
  *(float4*)&ao[(size_t)(r0 + r) * D_ + hd * 32 + j4] = o4;  // sorted space
}

// ---------------- routing (folds fc2 split-K partials x3): ------------------
__global__ __launch_bounds__(256) void route_kernel(float* __restrict__ h,
                                                    const float* __restrict__ pbuf,
                                                    const int* __restrict__ invord,
                                                    const float* __restrict__ dir_w,
                                                    const float* __restrict__ dir_b,
                                                    const float* __restrict__ at,
                                                    const float* __restrict__ mag_w,
                                                    const float* __restrict__ mag_b,
                                                    const float* __restrict__ delta,
                                                    int* __restrict__ node) {
  int p = blockIdx.x, t = threadIdx.x;
  __shared__ float hs[D_];
  __shared__ float dpart[8][AD_];
  __shared__ float dirs[AD_];
  __shared__ float scs[NN_];
  __shared__ float red[4];
  int ip = invord[p];
  float hv = h[(size_t)p * D_ + t];
#pragma unroll
  for (int q = 0; q < 3; q++) hv += pbuf[((size_t)q * PS_ + ip) * D_ + t];
  hs[t] = hv;
  __syncthreads();

  int j = t & 31, seg = t >> 5;
  float part = 0.0f;
#pragma unroll 8
  for (int i = 0; i < 32; i++) {
    int ii = seg * 32 + i;
    part += hs[ii] * dir_w[ii * D_ + j];
  }
  dpart[seg][j] = part;
  __syncthreads();
  if (t < AD_) {
    float s = dir_b[t];
#pragma unroll
    for (int g = 0; g < 8; g++) s += dpart[g][t];
    dirs[t] = s;
  }
  __syncthreads();
  if (t < NN_) {
    float s = 0.0f;
#pragma unroll
    for (int a = 0; a < AD_; a++) s += dirs[a] * at[t * AD_ + a];
    scs[t] = s;
  }
  __syncthreads();
  if (t == 0) {
    float best = scs[0];
    int arg = 0;
    for (int nn = 1; nn < NN_; nn++)
      if (scs[nn] > best) { best = scs[nn]; arg = nn; }  // first-max like jnp.argmax
    node[p] = arg;
  }
  float mag = block_sum256(hv * mag_w[t], red) + mag_b[0];
  float sig = 1.0f / (1.0f + __expf(-mag));
  h[(size_t)p * D_ + t] = hv + delta[(size_t)p * D_ + t] * sig;
}

// ---------------- final logits ----------------
__global__ __launch_bounds__(256) void out_kernel(const float* __restrict__ h,
                                                  const float* __restrict__ ow,
                                                  const float* __restrict__ ob,
                                                  float* __restrict__ out) {
  int p = blockIdx.x, t = threadIdx.x;
  __shared__ float hs[D_];
  __shared__ float part[8][NC_];
  hs[t] = h[(size_t)p * D_ + t];
  __syncthreads();
  int j = t & 31, seg = t >> 5;
  float s = 0.0f;
#pragma unroll 8
  for (int i = 0; i < 32; i++) {
    int ii = seg * 32 + i;
    s += hs[ii] * ow[ii * NC_ + j];
  }
  part[seg][j] = s;
  __syncthreads();
  if (t < NC_) {
    float r = ob[t];
#pragma unroll
    for (int g = 0; g < 8; g++) r += part[g][t];
    out[(size_t)p * NC_ + t] = r;
  }
}

extern "C" void kernel_launch(void* const* d_in, const int* in_sizes, int n_in,
                              void* d_out, int out_size, void* d_ws, size_t ws_size,
                              hipStream_t stream) {
  (void)in_sizes; (void)n_in; (void)out_size; (void)ws_size;
  const float* query_keys       = (const float*)d_in[0];
  const float* writer_keys      = (const float*)d_in[1];
  const float* key_proj_w       = (const float*)d_in[2];
  const float* key_proj_b       = (const float*)d_in[3];
  const float* class_embed      = (const float*)d_in[4];
  const float* role_embed       = (const float*)d_in[5];
  const float* start_node_embed = (const float*)d_in[6];
  const float* input_ln_g       = (const float*)d_in[7];
  const float* input_ln_b       = (const float*)d_in[8];
  const float* ln1_g            = (const float*)d_in[9];
  const float* ln1_b            = (const float*)d_in[10];
  const float* wqkv             = (const float*)d_in[11];
  const float* bqkv             = (const float*)d_in[12];
  const float* wo               = (const float*)d_in[13];
  const float* bo               = (const float*)d_in[14];
  const float* ln2_g            = (const float*)d_in[15];
  const float* ln2_b            = (const float*)d_in[16];
  const float* w_fc1            = (const float*)d_in[17];
  const float* b_fc1            = (const float*)d_in[18];
  const float* w_fc2            = (const float*)d_in[19];
  const float* b_fc2            = (const float*)d_in[20];
  const float* delta_w          = (const float*)d_in[21];
  const float* delta_b          = (const float*)d_in[22];
  const float* dir_w            = (const float*)d_in[23];
  const float* dir_b            = (const float*)d_in[24];
  const float* mag_w            = (const float*)d_in[25];
  const float* mag_b            = (const float*)d_in[26];
  const float* out_w            = (const float*)d_in[27];
  const float* out_b            = (const float*)d_in[28];
  const float* address_table    = (const float*)d_in[29];
  const int* query_start_nodes  = (const int*)d_in[30];
  const int* writer_labels      = (const int*)d_in[31];
  const int* writer_start_nodes = (const int*)d_in[32];

  uintptr_t basep = (uintptr_t)d_ws;
  auto carve = [&](size_t bytes) {
    basep = (basep + 255) & ~(uintptr_t)255;
    void* r = (void*)basep;
    basep += bytes;
    return r;
  };
  // Buffer roles (all padded +16 rows: tail tiles may load past P):
  //  h    : packet-space residual stream
  //  x    : sorted space: ln output / attn output (ao)
  //  buf1 : sorted qkv main [P x 768]; reused as delta out [P x 256]
  //  ff   : sorted fc1 output [P x 1024]
  //  pbuf : fc2 split-K partials [3][PS_][256] (folded by delta XMODE=1 + route)
  float* h    = (float*)carve((size_t)PS_ * D_ * 4);
  float* x    = (float*)carve((size_t)PS_ * D_ * 4);
  float* buf1 = (float*)carve((size_t)PS_ * DFF_ * 4);
  float* ff   = (float*)carve((size_t)PS_ * DFF_ * 4);
  float* pbuf = (float*)carve((size_t)3 * PS_ * D_ * 4);
  int* node   = (int*)carve(P_ * 4);
  int* order  = (int*)carve(P_ * 4);
  int* invord = (int*)carve(P_ * 4);
  int* offs   = (int*)carve(NN_ * 4);
  int* cnts   = (int*)carve(NN_ * 4);
  int* tnode  = (int*)carve(MAXT2_ * 4);
  int* tstart = (int*)carve(MAXT2_ * 4);
  int* tend   = (int*)carve(MAXT2_ * 4);
  int* ntiles = (int*)carve(4);

  encode_kernel<<<P_, 256, 0, stream>>>(query_keys, writer_keys, key_proj_w, key_proj_b,
                                        class_embed, role_embed, start_node_embed,
                                        input_ln_g, input_ln_b, query_start_nodes,
                                        writer_labels, writer_start_nodes, h, node);

  for (int hop = 0; hop < HOPS_; ++hop) {
    sort_kernel<<<1, 256, 0, stream>>>(node, order, invord, offs, cnts,
                                       tnode, tstart, tend, ntiles);
    ln_affine<<<P_ / 4, 256, 0, stream>>>(h, ln1_g, ln1_b, node, order, x);
    // qkv: [256 -> 768], RT=16, 3 col panels, sorted out
    glin5<256, 768, 16, 0, 0, 1, 1, 0><<<dim3(MAXT2_, 3), 256, 0, stream>>>(
        x, wqkv, bqkv, buf1, nullptr, nullptr, order, invord, tnode, tstart, tend,
        ntiles);
    attn_kernel<<<dim3(P_ / 32, NH_), 256, 0, stream>>>(buf1, node, order, offs,
                                                        cnts, x /*ao, sorted*/);
    // wo: [256 -> 256], RT=8 half-tiles (352 blocks), residual into h
    glin5<256, 256, 8, 0, 1, 1, 1, 0><<<dim3(MAXT2_ * 2, 1), 256, 0, stream>>>(
        x, wo, bo, h, nullptr, nullptr, order, invord, tnode, tstart, tend, ntiles);
    ln_affine<<<P_ / 4, 256, 0, stream>>>(h, ln2_g, ln2_b, node, order, x);
    // fc1: [256 -> 1024], RT=16, GELU, 4 col panels, sorted out
    glin5<256, 1024, 16, 1, 0, 1, 1, 0><<<dim3(MAXT2_, 4), 256, 0, stream>>>(
        x, w_fc1, b_fc1, ff, nullptr, nullptr, order, invord, tnode, tstart, tend,
        ntiles);
    // fc2: [1024 -> 256], RT=16, KSPLIT=4: z0 resid into h, z1..z3 -> pbuf
    glin5<1024, 256, 16, 0, 1, 1, 4, 0><<<dim3(MAXT2_, 1, 4), 256, 0, stream>>>(
        ff, w_fc2, b_fc2, h, pbuf, nullptr, order, invord, tnode, tstart, tend,
        ntiles);
    // delta = (h + sum pbuf) @ delta_w + delta_b (dense packet space, RT=8)
    glin5<256, 256, 8, 0, 0, 0, 1, 1><<<dim3(P_ / 8, 1), 256, 0, stream>>>(
        h, delta_w, delta_b, buf1 /*delta out*/, nullptr, pbuf, order, invord,
        tnode, tstart, tend, ntiles);
    route_kernel<<<P_, 256, 0, stream>>>(h, pbuf, invord, dir_w, dir_b, address_table,
                                         mag_w, mag_b, buf1, node);
  }

  out_kernel<<<P_, 256, 0, stream>>>(h, out_w, out_b, (float*)d_out);
}

// Round 6
// 1071.557 us; speedup vs baseline: 1.4314x; 1.4314x over previous
//
#include <hip/hip_runtime.h>
#include <math.h>

// Problem constants
#define B_    512
#define W_    4
#define KD_   64
#define NC_   32
#define D_    256
#define NN_   16
#define NH_   8
#define AD_   32
#define HOPS_ 4
#define DH_   32
#define DFF_  1024
#define P_    2560
#define BW_   2048   // B*W
#define MAXT_  56    // worst-case 64-row M-tiles: P/64 + (NN-1)
#define MAXT2_ 176   // worst-case 16-row M-tiles: P/16 + (NN-1) = 175 -> 176 (%8==0)
#define PS_   (P_ + 16)  // padded row stride

#define INV_SQRT_DH 0.17677669529663687f  // 1/sqrt(32)

typedef __attribute__((ext_vector_type(8))) short short8v;
typedef __attribute__((ext_vector_type(4))) float f32x4;

// ---------------- bf16 split helpers ----------------
__device__ __forceinline__ unsigned short bf16_rne(float f) {
  unsigned u = __float_as_uint(f);
  unsigned r = (u + 0x7fffu + ((u >> 16) & 1u)) >> 16;
  return (unsigned short)r;
}
__device__ __forceinline__ void split2(float v, unsigned short& h, unsigned short& l) {
  unsigned short hb = bf16_rne(v);
  float hf = __uint_as_float(((unsigned)hb) << 16);
  h = hb;
  l = bf16_rne(v - hf);
}

// ---------------- block-wide sum over 256 threads ----------------
__device__ __forceinline__ float block_sum256(float v, float* red) {
#pragma unroll
  for (int off = 32; off > 0; off >>= 1) v += __shfl_xor(v, off, 64);
  int wid = threadIdx.x >> 6;
  if ((threadIdx.x & 63) == 0) red[wid] = v;
  __syncthreads();
  float s = red[0] + red[1] + red[2] + red[3];
  __syncthreads();
  return s;
}

__device__ __forceinline__ float gelu_tanh(float v) {
  float u = 0.7978845608028654f * (v + 0.044715f * v * v * v);
  return 0.5f * v * (1.0f + tanhf(u));
}

// ---------------- zero the +16 pad rows of the bf16 activation buffers ------
__global__ __launch_bounds__(256) void padzero_kernel(unsigned short* __restrict__ xh,
                                                      unsigned short* __restrict__ xl,
                                                      unsigned short* __restrict__ ffh,
                                                      unsigned short* __restrict__ ffl) {
  int t = threadIdx.x;
  for (int i = t; i < 16 * D_; i += 256) {
    xh[(size_t)P_ * D_ + i] = 0;
    xl[(size_t)P_ * D_ + i] = 0;
  }
  for (int i = t; i < 16 * DFF_; i += 256) {
    ffh[(size_t)P_ * DFF_ + i] = 0;
    ffl[(size_t)P_ * DFF_ + i] = 0;
  }
}

// ---------------- encode writers + queries -> h, node ----------------
__global__ __launch_bounds__(256) void encode_kernel(
    const float* __restrict__ query_keys, const float* __restrict__ writer_keys,
    const float* __restrict__ kpw, const float* __restrict__ kpb,
    const float* __restrict__ ce, const float* __restrict__ re,
    const float* __restrict__ sne, const float* __restrict__ ilg,
    const float* __restrict__ ilb, const int* __restrict__ qsn,
    const int* __restrict__ wl, const int* __restrict__ wsn,
    float* __restrict__ h, int* __restrict__ node) {
  int p = blockIdx.x, t = threadIdx.x;
  __shared__ float fk[KD_];
  __shared__ float red[4];
  const float* key;
  int lab = -1, sn, role;
  if (p < BW_) { key = writer_keys + (size_t)p * KD_; lab = wl[p]; sn = wsn[p]; role = 0; }
  else { int b = p - BW_; key = query_keys + (size_t)b * KD_; sn = qsn[b]; role = 1; }
  if (t < KD_) fk[t] = key[t];
  __syncthreads();

  float acc = kpb[t] + sne[sn * D_ + t] + re[role * D_ + t];
  if (lab >= 0) acc += ce[lab * D_ + t];
#pragma unroll 8
  for (int i = 0; i < KD_; i++) acc += fk[i] * kpw[i * D_ + t];

  float mean = block_sum256(acc, red) * (1.0f / D_);
  float d = acc - mean;
  float var = block_sum256(d * d, red) * (1.0f / D_);
  float xn = d * (1.0f / sqrtf(var + 1e-5f));

  float sw = 0.0f;
  if (t < KD_) sw = fk[t];
  else if (lab >= 0 && t < KD_ + NC_) sw = (t - KD_ == lab) ? 1.0f : 0.0f;

  h[(size_t)p * D_ + t] = xn * ilg[t] + ilb[t] + sw;
  if (t == 0) node[p] = sn;
}

// ---------------- group packets by node + BOTH tile worklists ---------------
__global__ __launch_bounds__(256) void sort_kernel(const int* __restrict__ node,
                                                   int* __restrict__ order,
                                                   int* __restrict__ invord,
                                                   int* __restrict__ offs,
                                                   int* __restrict__ cnts,
                                                   int* __restrict__ tnode64,
                                                   int* __restrict__ tstart64,
                                                   int* __restrict__ tend64,
                                                   int* __restrict__ ntiles64,
                                                   int* __restrict__ tnode16,
                                                   int* __restrict__ tstart16,
                                                   int* __restrict__ tend16,
                                                   int* __restrict__ ntiles16) {
  __shared__ int c[NN_], o[NN_], cur[NN_];
  int t = threadIdx.x;
  if (t < NN_) c[t] = 0;
  __syncthreads();
  for (int p = t; p < P_; p += 256) atomicAdd(&c[node[p]], 1);
  __syncthreads();
  if (t == 0) {
    int s = 0;
    for (int n = 0; n < NN_; n++) { o[n] = s; cur[n] = s; s += c[n]; }
    int i64 = 0, i16 = 0;
    for (int n = 0; n < NN_; n++) {
      int e = o[n] + c[n];
      for (int m0 = o[n]; m0 < e; m0 += 64) {
        tnode64[i64] = n; tstart64[i64] = m0; tend64[i64] = e; i64++;
      }
      for (int m0 = o[n]; m0 < e; m0 += 16) {
        tnode16[i16] = n; tstart16[i16] = m0; tend16[i16] = e; i16++;
      }
    }
    ntiles64[0] = i64;
    ntiles16[0] = i16;
  }
  __syncthreads();
  if (t < NN_) { cnts[t] = c[t]; offs[t] = o[t]; }
  for (int p = t; p < P_; p += 256) {
    int r = atomicAdd(&cur[node[p]], 1);
    order[r] = p;
    invord[p] = r;
  }
}

// ---------------- LN with per-node affine -> split bf16 hi/lo, SORTED -------
__global__ __launch_bounds__(256) void ln_affine(const float* __restrict__ h,
                                                 const float* __restrict__ g,
                                                 const float* __restrict__ b,
                                                 const int* __restrict__ node,
                                                 const int* __restrict__ order,
                                                 unsigned short* __restrict__ xh,
                                                 unsigned short* __restrict__ xl) {
  int sp = blockIdx.x * 4 + (threadIdx.x >> 6);
  int lane = threadIdx.x & 63;
  int p = order[sp];
  int n = node[p];
  float4 v = *(const float4*)&h[(size_t)p * D_ + lane * 4];
  float s = v.x + v.y + v.z + v.w;
#pragma unroll
  for (int off = 32; off > 0; off >>= 1) s += __shfl_xor(s, off, 64);
  float mean = s * (1.0f / D_);
  float4 d = make_float4(v.x - mean, v.y - mean, v.z - mean, v.w - mean);
  float vr = d.x * d.x + d.y * d.y + d.z * d.z + d.w * d.w;
#pragma unroll
  for (int off = 32; off > 0; off >>= 1) vr += __shfl_xor(vr, off, 64);
  float inv = 1.0f / sqrtf(vr * (1.0f / D_) + 1e-5f);
  float4 gg = *(const float4*)&g[n * D_ + lane * 4];
  float4 bb = *(const float4*)&b[n * D_ + lane * 4];
  float o[4];
  o[0] = d.x * inv * gg.x + bb.x;
  o[1] = d.y * inv * gg.y + bb.y;
  o[2] = d.z * inv * gg.z + bb.z;
  o[3] = d.w * inv * gg.w + bb.w;
  ushort4 oh, ol;
  split2(o[0], oh.x, ol.x);
  split2(o[1], oh.y, ol.y);
  split2(o[2], oh.z, ol.z);
  split2(o[3], oh.w, ol.w);
  *(ushort4*)&xh[(size_t)sp * D_ + lane * 4] = oh;
  *(ushort4*)&xl[(size_t)sp * D_ + lane * 4] = ol;
}

// ---------------- weight prep: W[n][k][c] f32 -> Wt hi/lo [n][c][k] bf16 ----
template <int K, int C>
__global__ __launch_bounds__(256) void wprep(const float* __restrict__ W,
                                             unsigned short* __restrict__ th,
                                             unsigned short* __restrict__ tl) {
  __shared__ float ld[32][33];
  int n = blockIdx.z;
  int k0 = blockIdx.x * 32, c0 = blockIdx.y * 32;
  int tx = threadIdx.x & 31, ty = threadIdx.x >> 5;  // 32 x 8
  const float* Wn = W + (size_t)n * K * C;
#pragma unroll
  for (int i = 0; i < 32; i += 8)
    ld[i + ty][tx] = Wn[(size_t)(k0 + i + ty) * C + c0 + tx];
  __syncthreads();
#pragma unroll
  for (int i = 0; i < 32; i += 8) {
    float v = ld[tx][i + ty];
    unsigned short hh, ll;
    split2(v, hh, ll);
    size_t off = ((size_t)n * C + c0 + i + ty) * K + k0 + tx;
    th[off] = hh;
    tl[off] = ll;
  }
}

// ---------------- grouped linear via MFMA (bf16x3 fp32 emulation) -----------
// Block = 256 thr = 4 waves; wave wv owns a 16x16 output tile: rows = the
// 16-row node-tile, cols = blockIdx.y*64 + wv*16. No LDS, no barriers.
// A-frag: x row = lane&15, k = (lane>>4)*8..+8 (16B contiguous, L1-hot).
// B-frag: Wt[n][col][k], col = lane&15, same k-map (B operand is implicitly
// transposed, so D = x @ W).
// C/D: col = lane&15, row = (lane>>4)*4 + reg  [m89-verified].
// acc = xh*Wh + xh*Wl + xl*Wh in 3 independent chains (~fp32-grade).
template <int DIN, int DOUT, int ACT, int RESID, int SPLITOUT>
__global__ __launch_bounds__(256) void gmfma(
    const unsigned short* __restrict__ xh, const unsigned short* __restrict__ xl,
    const unsigned short* __restrict__ wth, const unsigned short* __restrict__ wtl,
    const float* __restrict__ bias, float* __restrict__ outf,
    unsigned short* __restrict__ outh, unsigned short* __restrict__ outl,
    const int* __restrict__ order, const int* __restrict__ tnode,
    const int* __restrict__ tstart, const int* __restrict__ tend,
    const int* __restrict__ ntiles) {
  int gx = gridDim.x;
  int bid = blockIdx.x;
  int ti = (bid & 7) * (gx >> 3) + (bid >> 3);  // bijective XCD swizzle (gx%8==0)
  if (ti >= ntiles[0]) return;
  int n = tnode[ti];
  int s0 = tstart[ti];
  int rows = tend[ti] - s0;
  if (rows <= 0) return;
  if (rows > 16) rows = 16;

  int tid = threadIdx.x;
  int wv = tid >> 6;
  int lane = tid & 63;
  int r16 = lane & 15;
  int kg = lane >> 4;  // 0..3
  int jcol = blockIdx.y * 64 + wv * 16;

  const unsigned short* pah = xh + (size_t)(s0 + r16) * DIN + kg * 8;
  const unsigned short* pal = xl + (size_t)(s0 + r16) * DIN + kg * 8;
  const unsigned short* pbh = wth + ((size_t)n * DOUT + jcol + r16) * DIN + kg * 8;
  const unsigned short* pbl = wtl + ((size_t)n * DOUT + jcol + r16) * DIN + kg * 8;

  f32x4 acc0 = {0.f, 0.f, 0.f, 0.f};
  f32x4 acc1 = acc0, acc2 = acc0;
#pragma unroll 4
  for (int k0 = 0; k0 < DIN; k0 += 32) {
    short8v ah = *(const short8v*)(pah + k0);
    short8v al = *(const short8v*)(pal + k0);
    short8v bh = *(const short8v*)(pbh + k0);
    short8v bl = *(const short8v*)(pbl + k0);
    acc0 = __builtin_amdgcn_mfma_f32_16x16x32_bf16(ah, bh, acc0, 0, 0, 0);
    acc1 = __builtin_amdgcn_mfma_f32_16x16x32_bf16(ah, bl, acc1, 0, 0, 0);
    acc2 = __builtin_amdgcn_mfma_f32_16x16x32_bf16(al, bh, acc2, 0, 0, 0);
  }

  float bv = bias[(size_t)n * DOUT + jcol + r16];
#pragma unroll
  for (int rg = 0; rg < 4; rg++) {
    int r = kg * 4 + rg;
    if (r >= rows) continue;
    float v = acc0[rg] + acc1[rg] + acc2[rg] + bv;
    if (ACT) v = gelu_tanh(v);
    if (SPLITOUT) {
      size_t off = (size_t)(s0 + r) * DOUT + jcol + r16;
      unsigned short hh, ll;
      split2(v, hh, ll);
      outh[off] = hh;
      outl[off] = ll;
    } else if (RESID) {
      int pp = order[s0 + r];
      float* op = outf + (size_t)pp * DOUT + jcol + r16;
      *op += v;
    } else {
      outf[(size_t)(s0 + r) * DOUT + jcol + r16] = v;
    }
  }
}

// ---------------- grouped linear (R0 vector version, verbatim) --------------
template <int DIN, int DOUT, int JT, int ACT, int RESID, int PER_NODE, int KSPLIT, int XMODE>
__global__ __launch_bounds__(256) void glin(const float* __restrict__ x,
                                            const float* __restrict__ W,
                                            const float* __restrict__ bias,
                                            float* __restrict__ out,
                                            float* __restrict__ pbuf,
                                            const float* __restrict__ xaux,
                                            const int* __restrict__ order,
                                            const int* __restrict__ invord,
                                            const int* __restrict__ tnode,
                                            const int* __restrict__ tstart,
                                            const int* __restrict__ tend,
                                            const int* __restrict__ ntiles) {
  constexpr int KC = 32, STX = 68;
  constexpr int CPT = JT / 16;
  constexpr int HALF = 64;
  constexpr int KLEN = DIN / KSPLIT;
  constexpr int NCH = KLEN / KC;
  constexpr int LPR = JT / 4;
  constexpr int RPI = 64 / LPR;

  int ti = blockIdx.x;
  int n, s0, s1;
  if (PER_NODE) {
    if (ti >= ntiles[0]) return;
    n = tnode[ti]; s0 = tstart[ti]; s1 = tend[ti];
  } else {
    n = 0; s0 = ti * 64; s1 = P_;
  }
  int jbase = blockIdx.y * JT;
  int kz = (KSPLIT > 1) ? blockIdx.z : 0;
  int k0 = kz * KLEN;
  int rows = s1 - s0; if (rows > 64) rows = 64;

  __shared__ float xs[2][KC][STX];
  __shared__ float ws[2][KC][JT];

  int tid = threadIdx.x;
  const float* Wn = W + (size_t)n * DIN * DOUT + jbase;

  int xrow = tid >> 2, xq = tid & 3;
  bool xvalid = xrow < rows;
  const float* xptr = x + (size_t)(s0 + (xvalid ? xrow : 0)) * DIN + k0 + xq * 4;
  const float* aptr = nullptr;
  if (XMODE == 1) {
    int pr = xvalid ? invord[s0 + xrow] : 0;
    aptr = xaux + (size_t)pr * DIN + k0 + xq * 4;
  }

  float4 xr0, xr1;
  auto xfetch = [&](int kc) {
    if (xvalid) {
      xr0 = *(const float4*)(xptr + kc);
      xr1 = *(const float4*)(xptr + kc + 16);
      if (XMODE == 1) {
        float4 p0 = *(const float4*)(aptr + kc);
        float4 p1 = *(const float4*)(aptr + kc + 16);
        xr0.x += p0.x; xr0.y += p0.y; xr0.z += p0.z; xr0.w += p0.w;
        xr1.x += p1.x; xr1.y += p1.y; xr1.z += p1.z; xr1.w += p1.w;
      }
    } else {
      xr0 = make_float4(0.f, 0.f, 0.f, 0.f);
      xr1 = make_float4(0.f, 0.f, 0.f, 0.f);
    }
  };
  auto xstage = [&](int buf) {
    xs[buf][xq * 4 + 0][xrow] = xr0.x;
    xs[buf][xq * 4 + 1][xrow] = xr0.y;
    xs[buf][xq * 4 + 2][xrow] = xr0.z;
    xs[buf][xq * 4 + 3][xrow] = xr0.w;
    xs[buf][xq * 4 + 16][xrow] = xr1.x;
    xs[buf][xq * 4 + 17][xrow] = xr1.y;
    xs[buf][xq * 4 + 18][xrow] = xr1.z;
    xs[buf][xq * 4 + 19][xrow] = xr1.w;
  };
  int wvw = tid >> 6, lane = tid & 63;
  int wlr = lane / LPR;
  int wlc = (lane % LPR) * 4;
  auto wfetch = [&](int buf, int kc) {
#pragma unroll
    for (int i = 0; i < 8 / RPI; i++) {
      int kr = wvw * 8 + i * RPI;
      const float* g = &Wn[(size_t)(k0 + kc + kr + wlr) * DOUT + wlc];
      __builtin_amdgcn_global_load_lds(
          (const __attribute__((address_space(1))) unsigned int*)g,
          (__attribute__((address_space(3))) unsigned int*)&ws[buf][kr][0],
          16, 0, 0);
    }
  };

  wfetch(0, 0);
  xfetch(0);
  xstage(0);
  __syncthreads();

  int r4 = (tid >> 4) * 4;
  int jc4 = (tid & 15) * 4;
  float acc[4][CPT];
#pragma unroll
  for (int r = 0; r < 4; r++)
#pragma unroll
    for (int cc = 0; cc < CPT; cc++) acc[r][cc] = 0.f;

  for (int c = 0; c < NCH; c++) {
    int cur = c & 1;
    if (c + 1 < NCH) {
      wfetch(cur ^ 1, (c + 1) * KC);
      xfetch((c + 1) * KC);
    }
#pragma unroll 8
    for (int k = 0; k < KC; k++) {
      float4 a = *(const float4*)&xs[cur][k][r4];
      float av[4] = {a.x, a.y, a.z, a.w};
      float bv[CPT];
      float4 b0 = *(const float4*)&ws[cur][k][jc4];
      bv[0] = b0.x; bv[1] = b0.y; bv[2] = b0.z; bv[3] = b0.w;
      if (CPT == 8) {
        float4 b1 = *(const float4*)&ws[cur][k][jc4 + HALF];
        bv[4] = b1.x; bv[5] = b1.y; bv[6] = b1.z; bv[7] = b1.w;
      }
#pragma unroll
      for (int r = 0; r < 4; r++)
#pragma unroll
        for (int cc = 0; cc < CPT; cc++) acc[r][cc] += av[r] * bv[cc];
    }
    if (c + 1 < NCH) xstage(cur ^ 1);
    __syncthreads();
  }

  bool main_part = (KSPLIT == 1) || (kz == 0);
  float bbv[CPT];
#pragma unroll
  for (int cc = 0; cc < 4; cc++) bbv[cc] = bias[n * DOUT + jbase + jc4 + cc];
  if (CPT == 8) {
#pragma unroll
    for (int cc = 0; cc < 4; cc++) bbv[4 + cc] = bias[n * DOUT + jbase + jc4 + HALF + cc];
  }

#pragma unroll
  for (int r = 0; r < 4; r++) {
    int lr = r4 + r;
    if (lr >= rows) continue;
    float v[CPT];
    if (main_part) {
#pragma unroll
      for (int cc = 0; cc < CPT; cc++) {
        v[cc] = acc[r][cc] + bbv[cc];
        if (ACT == 1) v[cc] = gelu_tanh(v[cc]);
      }
      if (RESID) {
        int pp = PER_NODE ? order[s0 + lr] : (s0 + lr);
        float* op = &out[(size_t)pp * DOUT + jbase + jc4];
        {
          float4 old = *(const float4*)op;
          *(float4*)op = make_float4(v[0] + old.x, v[1] + old.y, v[2] + old.z, v[3] + old.w);
        }
        if (CPT == 8) {
          float4 old = *(const float4*)(op + HALF);
          *(float4*)(op + HALF) =
              make_float4(v[4] + old.x, v[5] + old.y, v[6] + old.z, v[7] + old.w);
        }
      } else {
        float* op = &out[(size_t)(s0 + lr) * DOUT + jbase + jc4];
        *(float4*)op = make_float4(v[0], v[1], v[2], v[3]);
        if (CPT == 8)
          *(float4*)(op + HALF) = make_float4(v[4], v[5], v[6], v[7]);
      }
    } else {
      float* op = &pbuf[(size_t)(s0 + lr) * DOUT + jbase + jc4];
      *(float4*)op = make_float4(acc[r][0], acc[r][1], acc[r][2], acc[r][3]);
      if (CPT == 8)
        *(float4*)(op + HALF) = make_float4(acc[r][4], acc[r][5], acc[r][6], acc[r][7]);
    }
  }
}

// ---------------- same-node attention, flash-style, sorted qkv/ao ----------
#define ATS 36
__global__ __launch_bounds__(256) void attn_kernel(const float* __restrict__ qkv,
                                                   const int* __restrict__ node,
                                                   const int* __restrict__ order,
                                                   const int* __restrict__ offs,
                                                   const int* __restrict__ cnts,
                                                   float* __restrict__ ao) {
  __shared__ float qs[32 * ATS];
  __shared__ float kts[32 * ATS];
  __shared__ float vs[32 * ATS];
  __shared__ float ps[32 * ATS];
  __shared__ int glo[32], ghi[32];

  int t = threadIdx.x;
  int r = t >> 3;
  int j4 = (t & 7) * 4;
  int r0 = blockIdx.x * 32;
  int hd = blockIdx.y;

  if (t < 32) {
    int n = node[order[r0 + t]];
    glo[t] = offs[n];
    ghi[t] = offs[n] + cnts[n];
  }
  __syncthreads();

  {
    const float* qp = &qkv[(size_t)(r0 + r) * 768 + hd * 32 + j4];
    float4 q4 = *(const float4*)qp;
    q4.x *= INV_SQRT_DH; q4.y *= INV_SQRT_DH; q4.z *= INV_SQRT_DH; q4.w *= INV_SQRT_DH;
    *(float4*)&qs[r * ATS + j4] = q4;
  }

  int lo = glo[0];
  int hi = ghi[31];
  int myglo = glo[r], myghi = ghi[r];

  float4 o4 = {0.f, 0.f, 0.f, 0.f};
  float mrow = -1e30f, lrow = 0.f;

  for (int kt = lo; kt < hi; kt += 32) {
    int sj = kt + r;
    float4 k4 = {0.f, 0.f, 0.f, 0.f}, v4 = {0.f, 0.f, 0.f, 0.f};
    if (sj < hi) {
      const float* kp = &qkv[(size_t)sj * 768 + 256 + hd * 32 + j4];
      k4 = *(const float4*)kp;
      v4 = *(const float4*)(kp + 256);
    }
    __syncthreads();
    kts[(j4 + 0) * ATS + r] = k4.x;
    kts[(j4 + 1) * ATS + r] = k4.y;
    kts[(j4 + 2) * ATS + r] = k4.z;
    kts[(j4 + 3) * ATS + r] = k4.w;
    *(float4*)&vs[r * ATS + j4] = v4;
    __syncthreads();

    float s0 = 0.f, s1 = 0.f, s2 = 0.f, s3 = 0.f;
#pragma unroll 8
    for (int d = 0; d < 32; d++) {
      float qv = qs[r * ATS + d];
      float4 kv = *(const float4*)&kts[d * ATS + j4];
      s0 += qv * kv.x; s1 += qv * kv.y; s2 += qv * kv.z; s3 += qv * kv.w;
    }
    int c0 = kt + j4;
    if (c0 + 0 < myglo || c0 + 0 >= myghi) s0 = -1e30f;
    if (c0 + 1 < myglo || c0 + 1 >= myghi) s1 = -1e30f;
    if (c0 + 2 < myglo || c0 + 2 >= myghi) s2 = -1e30f;
    if (c0 + 3 < myglo || c0 + 3 >= myghi) s3 = -1e30f;

    float mx = fmaxf(fmaxf(s0, s1), fmaxf(s2, s3));
#pragma unroll
    for (int off = 4; off > 0; off >>= 1) mx = fmaxf(mx, __shfl_xor(mx, off, 8));
    float mnew = fmaxf(mrow, mx);
    float alpha = __expf(mrow - mnew);
    float p0 = __expf(s0 - mnew), p1 = __expf(s1 - mnew);
    float p2 = __expf(s2 - mnew), p3 = __expf(s3 - mnew);
    float ls = p0 + p1 + p2 + p3;
#pragma unroll
    for (int off = 4; off > 0; off >>= 1) ls += __shfl_xor(ls, off, 8);
    lrow = lrow * alpha + ls;
    mrow = mnew;
    o4.x *= alpha; o4.y *= alpha; o4.z *= alpha; o4.w *= alpha;

    *(float4*)&ps[r * ATS + j4] = make_float4(p0, p1, p2, p3);
#pragma unroll 8
    for (int j = 0; j < 32; j++) {
      float pj = ps[r * ATS + j];
      float4 vv = *(const float4*)&vs[j * ATS + j4];
      o4.x += pj * vv.x; o4.y += pj * vv.y; o4.z += pj * vv.z; o4.w += pj * vv.w;
    }
  }

  float inv = 1.f / lrow;
  o4.x *= inv; o4.y *= inv; o4.z *= inv; o4.w *= inv;
  *(float4*)&ao[(size_t)(r0 + r) * D_ + hd * 32 + j4] = o4;
}

// ---------------- routing ----------------
__global__ __launch_bounds__(256) void route_kernel(float* __restrict__ h,
                                                    const float* __restrict__ dir_w,
                                                    const float* __restrict__ dir_b,
                                                    const float* __restrict__ at,
                                                    const float* __restrict__ mag_w,
                                                    const float* __restrict__ mag_b,
                                                    const float* __restrict__ delta,
                                                    int* __restrict__ node) {
  int p = blockIdx.x, t = threadIdx.x;
  __shared__ float hs[D_];
  __shared__ float dpart[8][AD_];
  __shared__ float dirs[AD_];
  __shared__ float scs[NN_];
  __shared__ float red[4];
  float hv = h[(size_t)p * D_ + t];
  hs[t] = hv;
  __syncthreads();

  int j = t & 31, seg = t >> 5;
  float part = 0.0f;
#pragma unroll 8
  for (int i = 0; i < 32; i++) {
    int ii = seg * 32 + i;
    part += hs[ii] * dir_w[ii * D_ + j];
  }
  dpart[seg][j] = part;
  __syncthreads();
  if (t < AD_) {
    float s = dir_b[t];
#pragma unroll
    for (int g = 0; g < 8; g++) s += dpart[g][t];
    dirs[t] = s;
  }
  __syncthreads();
  if (t < NN_) {
    float s = 0.0f;
#pragma unroll
    for (int a = 0; a < AD_; a++) s += dirs[a] * at[t * AD_ + a];
    scs[t] = s;
  }
  __syncthreads();
  if (t == 0) {
    float best = scs[0];
    int arg = 0;
    for (int nn = 1; nn < NN_; nn++)
      if (scs[nn] > best) { best = scs[nn]; arg = nn; }
    node[p] = arg;
  }
  float mag = block_sum256(hv * mag_w[t], red) + mag_b[0];
  float sig = 1.0f / (1.0f + __expf(-mag));
  h[(size_t)p * D_ + t] = hv + delta[(size_t)p * D_ + t] * sig;
}

// ---------------- final logits ----------------
__global__ __launch_bounds__(256) void out_kernel(const float* __restrict__ h,
                                                  const float* __restrict__ ow,
                                                  const float* __restrict__ ob,
                                                  float* __restrict__ out) {
  int p = blockIdx.x, t = threadIdx.x;
  __shared__ float hs[D_];
  __shared__ float part[8][NC_];
  hs[t] = h[(size_t)p * D_ + t];
  __syncthreads();
  int j = t & 31, seg = t >> 5;
  float s = 0.0f;
#pragma unroll 8
  for (int i = 0; i < 32; i++) {
    int ii = seg * 32 + i;
    s += hs[ii] * ow[ii * NC_ + j];
  }
  part[seg][j] = s;
  __syncthreads();
  if (t < NC_) {
    float r = ob[t];
#pragma unroll
    for (int g = 0; g < 8; g++) r += part[g][t];
    out[(size_t)p * NC_ + t] = r;
  }
}

extern "C" void kernel_launch(void* const* d_in, const int* in_sizes, int n_in,
                              void* d_out, int out_size, void* d_ws, size_t ws_size,
                              hipStream_t stream) {
  (void)in_sizes; (void)n_in; (void)out_size; (void)ws_size;
  const float* query_keys       = (const float*)d_in[0];
  const float* writer_keys      = (const float*)d_in[1];
  const float* key_proj_w       = (const float*)d_in[2];
  const float* key_proj_b       = (const float*)d_in[3];
  const float* class_embed      = (const float*)d_in[4];
  const float* role_embed       = (const float*)d_in[5];
  const float* start_node_embed = (const float*)d_in[6];
  const float* input_ln_g       = (const float*)d_in[7];
  const float* input_ln_b       = (const float*)d_in[8];
  const float* ln1_g            = (const float*)d_in[9];
  const float* ln1_b            = (const float*)d_in[10];
  const float* wqkv             = (const float*)d_in[11];
  const float* bqkv             = (const float*)d_in[12];
  const float* wo               = (const float*)d_in[13];
  const float* bo               = (const float*)d_in[14];
  const float* ln2_g            = (const float*)d_in[15];
  const float* ln2_b            = (const float*)d_in[16];
  const float* w_fc1            = (const float*)d_in[17];
  const float* b_fc1            = (const float*)d_in[18];
  const float* w_fc2            = (const float*)d_in[19];
  const float* b_fc2            = (const float*)d_in[20];
  const float* delta_w          = (const float*)d_in[21];
  const float* delta_b          = (const float*)d_in[22];
  const float* dir_w            = (const float*)d_in[23];
  const float* dir_b            = (const float*)d_in[24];
  const float* mag_w            = (const float*)d_in[25];
  const float* mag_b            = (const float*)d_in[26];
  const float* out_w            = (const float*)d_in[27];
  const float* out_b            = (const float*)d_in[28];
  const float* address_table    = (const float*)d_in[29];
  const int* query_start_nodes  = (const int*)d_in[30];
  const int* writer_labels      = (const int*)d_in[31];
  const int* writer_start_nodes = (const int*)d_in[32];

  uintptr_t basep = (uintptr_t)d_ws;
  auto carve = [&](size_t bytes) {
    basep = (basep + 255) & ~(uintptr_t)255;
    void* r = (void*)basep;
    basep += bytes;
    return r;
  };
  float* h    = (float*)carve((size_t)P_ * D_ * 4);
  float* x    = (float*)carve((size_t)P_ * D_ * 4);             // ao f32 (sorted)
  float* buf1 = (float*)carve((size_t)P_ * 768 * 4);            // qkv f32; delta out
  unsigned short* xh  = (unsigned short*)carve((size_t)PS_ * D_ * 2);
  unsigned short* xl  = (unsigned short*)carve((size_t)PS_ * D_ * 2);
  unsigned short* ffh = (unsigned short*)carve((size_t)PS_ * DFF_ * 2);
  unsigned short* ffl = (unsigned short*)carve((size_t)PS_ * DFF_ * 2);
  unsigned short* wtqh = (unsigned short*)carve((size_t)NN_ * 768 * 256 * 2);
  unsigned short* wtql = (unsigned short*)carve((size_t)NN_ * 768 * 256 * 2);
  unsigned short* wt1h = (unsigned short*)carve((size_t)NN_ * 1024 * 256 * 2);
  unsigned short* wt1l = (unsigned short*)carve((size_t)NN_ * 1024 * 256 * 2);
  unsigned short* wt2h = (unsigned short*)carve((size_t)NN_ * 256 * 1024 * 2);
  unsigned short* wt2l = (unsigned short*)carve((size_t)NN_ * 256 * 1024 * 2);
  int* node   = (int*)carve(P_ * 4);
  int* order  = (int*)carve(P_ * 4);
  int* invord = (int*)carve(P_ * 4);
  int* offs   = (int*)carve(NN_ * 4);
  int* cnts   = (int*)carve(NN_ * 4);
  int* tnode64  = (int*)carve(MAXT_ * 4);
  int* tstart64 = (int*)carve(MAXT_ * 4);
  int* tend64   = (int*)carve(MAXT_ * 4);
  int* ntiles64 = (int*)carve(4);
  int* tnode16  = (int*)carve(MAXT2_ * 4);
  int* tstart16 = (int*)carve(MAXT2_ * 4);
  int* tend16   = (int*)carve(MAXT2_ * 4);
  int* ntiles16 = (int*)carve(4);

  // pad-row zeroing + one-time weight transpose+split (weights hop-invariant)
  padzero_kernel<<<1, 256, 0, stream>>>(xh, xl, ffh, ffl);
  wprep<256, 768><<<dim3(8, 24, NN_), 256, 0, stream>>>(wqkv, wtqh, wtql);
  wprep<256, 1024><<<dim3(8, 32, NN_), 256, 0, stream>>>(w_fc1, wt1h, wt1l);
  wprep<1024, 256><<<dim3(32, 8, NN_), 256, 0, stream>>>(w_fc2, wt2h, wt2l);

  encode_kernel<<<P_, 256, 0, stream>>>(query_keys, writer_keys, key_proj_w, key_proj_b,
                                        class_embed, role_embed, start_node_embed,
                                        input_ln_g, input_ln_b, query_start_nodes,
                                        writer_labels, writer_start_nodes, h, node);

  for (int hop = 0; hop < HOPS_; ++hop) {
    sort_kernel<<<1, 256, 0, stream>>>(node, order, invord, offs, cnts,
                                       tnode64, tstart64, tend64, ntiles64,
                                       tnode16, tstart16, tend16, ntiles16);
    ln_affine<<<P_ / 4, 256, 0, stream>>>(h, ln1_g, ln1_b, node, order, xh, xl);
    // qkv: [256 -> 768] MFMA, 12 col panels of 64, sorted f32 out
    gmfma<256, 768, 0, 0, 0><<<dim3(MAXT2_, 12), 256, 0, stream>>>(
        xh, xl, wtqh, wtql, bqkv, buf1, nullptr, nullptr, order,
        tnode16, tstart16, tend16, ntiles16);
    attn_kernel<<<dim3(P_ / 32, NH_), 256, 0, stream>>>(buf1, node, order, offs,
                                                        cnts, x /*ao, sorted*/);
    // wo: [256 -> 256] vector glin (R0), residual into h
    glin<256, 256, 64, 0, 1, 1, 1, 0><<<dim3(MAXT_, 4), 256, 0, stream>>>(
        x, wo, bo, h, nullptr, nullptr, order, invord, tnode64, tstart64, tend64,
        ntiles64);
    ln_affine<<<P_ / 4, 256, 0, stream>>>(h, ln2_g, ln2_b, node, order, xh, xl);
    // fc1: [256 -> 1024] MFMA + GELU, split bf16 out
    gmfma<256, 1024, 1, 0, 1><<<dim3(MAXT2_, 16), 256, 0, stream>>>(
        xh, xl, wt1h, wt1l, b_fc1, nullptr, ffh, ffl, order,
        tnode16, tstart16, tend16, ntiles16);
    // fc2: [1024 -> 256] MFMA, residual into h (packet space)
    gmfma<1024, 256, 0, 1, 0><<<dim3(MAXT2_, 4), 256, 0, stream>>>(
        ffh, ffl, wt2h, wt2l, b_fc2, h, nullptr, nullptr, order,
        tnode16, tstart16, tend16, ntiles16);
    // delta = h @ delta_w + delta_b (dense packet space, vector glin)
    glin<256, 256, 64, 0, 0, 0, 1, 0><<<dim3(P_ / 64, 4), 256, 0, stream>>>(
        h, delta_w, delta_b, buf1 /*delta out*/, nullptr, nullptr, order, invord,
        tnode64, tstart64, tend64, ntiles64);
    route_kernel<<<P_, 256, 0, stream>>>(h, dir_w, dir_b, address_table,
                                         mag_w, mag_b, buf1, node);
  }

  out_kernel<<<P_, 256, 0, stream>>>(h, out_w, out_b, (float*)d_out);
}

// Round 7
// 930.916 us; speedup vs baseline: 1.6476x; 1.1511x over previous
//
#include <hip/hip_runtime.h>
#include <math.h>

// Problem constants
#define B_    512
#define W_    4
#define KD_   64
#define NC_   32
#define D_    256
#define NN_   16
#define NH_   8
#define AD_   32
#define HOPS_ 4
#define DH_   32
#define DFF_  1024
#define P_    2560
#define BW_   2048   // B*W
#define MAXT_  56    // worst-case 64-row M-tiles: P/64 + (NN-1)
#define MAXT2_ 176   // worst-case 16-row M-tiles: P/16 + (NN-1) = 175 -> 176 (%8==0)
#define PS_   (P_ + 16)  // padded row stride

#define INV_SQRT_DH 0.17677669529663687f  // 1/sqrt(32)

typedef __attribute__((ext_vector_type(8))) short short8v;
typedef __attribute__((ext_vector_type(4))) float f32x4;

// ---------------- bf16 split helpers ----------------
__device__ __forceinline__ unsigned short bf16_rne(float f) {
  unsigned u = __float_as_uint(f);
  unsigned r = (u + 0x7fffu + ((u >> 16) & 1u)) >> 16;
  return (unsigned short)r;
}
__device__ __forceinline__ void split2(float v, unsigned short& h, unsigned short& l) {
  unsigned short hb = bf16_rne(v);
  float hf = __uint_as_float(((unsigned)hb) << 16);
  h = hb;
  l = bf16_rne(v - hf);
}

// ---------------- block-wide sum over 256 threads ----------------
__device__ __forceinline__ float block_sum256(float v, float* red) {
#pragma unroll
  for (int off = 32; off > 0; off >>= 1) v += __shfl_xor(v, off, 64);
  int wid = threadIdx.x >> 6;
  if ((threadIdx.x & 63) == 0) red[wid] = v;
  __syncthreads();
  float s = red[0] + red[1] + red[2] + red[3];
  __syncthreads();
  return s;
}

__device__ __forceinline__ float gelu_tanh(float v) {
  float u = 0.7978845608028654f * (v + 0.044715f * v * v * v);
  return 0.5f * v * (1.0f + tanhf(u));
}

// ---------------- zero the +16 pad rows of the bf16 activation buffers ------
__global__ __launch_bounds__(256) void padzero_kernel(unsigned short* __restrict__ xh,
                                                      unsigned short* __restrict__ xl,
                                                      unsigned short* __restrict__ ffh,
                                                      unsigned short* __restrict__ ffl) {
  int t = threadIdx.x;
  for (int i = t; i < 16 * D_; i += 256) {
    xh[(size_t)P_ * D_ + i] = 0;
    xl[(size_t)P_ * D_ + i] = 0;
  }
  for (int i = t; i < 16 * DFF_; i += 256) {
    ffh[(size_t)P_ * DFF_ + i] = 0;
    ffl[(size_t)P_ * DFF_ + i] = 0;
  }
}

// ---------------- encode writers + queries -> h, node ----------------
__global__ __launch_bounds__(256) void encode_kernel(
    const float* __restrict__ query_keys, const float* __restrict__ writer_keys,
    const float* __restrict__ kpw, const float* __restrict__ kpb,
    const float* __restrict__ ce, const float* __restrict__ re,
    const float* __restrict__ sne, const float* __restrict__ ilg,
    const float* __restrict__ ilb, const int* __restrict__ qsn,
    const int* __restrict__ wl, const int* __restrict__ wsn,
    float* __restrict__ h, int* __restrict__ node) {
  int p = blockIdx.x, t = threadIdx.x;
  __shared__ float fk[KD_];
  __shared__ float red[4];
  const float* key;
  int lab = -1, sn, role;
  if (p < BW_) { key = writer_keys + (size_t)p * KD_; lab = wl[p]; sn = wsn[p]; role = 0; }
  else { int b = p - BW_; key = query_keys + (size_t)b * KD_; sn = qsn[b]; role = 1; }
  if (t < KD_) fk[t] = key[t];
  __syncthreads();

  float acc = kpb[t] + sne[sn * D_ + t] + re[role * D_ + t];
  if (lab >= 0) acc += ce[lab * D_ + t];
#pragma unroll 8
  for (int i = 0; i < KD_; i++) acc += fk[i] * kpw[i * D_ + t];

  float mean = block_sum256(acc, red) * (1.0f / D_);
  float d = acc - mean;
  float var = block_sum256(d * d, red) * (1.0f / D_);
  float xn = d * (1.0f / sqrtf(var + 1e-5f));

  float sw = 0.0f;
  if (t < KD_) sw = fk[t];
  else if (lab >= 0 && t < KD_ + NC_) sw = (t - KD_ == lab) ? 1.0f : 0.0f;

  h[(size_t)p * D_ + t] = xn * ilg[t] + ilb[t] + sw;
  if (t == 0) node[p] = sn;
}

// ---------------- group packets by node + BOTH tile worklists ---------------
__global__ __launch_bounds__(256) void sort_kernel(const int* __restrict__ node,
                                                   int* __restrict__ order,
                                                   int* __restrict__ invord,
                                                   int* __restrict__ offs,
                                                   int* __restrict__ cnts,
                                                   int* __restrict__ tnode64,
                                                   int* __restrict__ tstart64,
                                                   int* __restrict__ tend64,
                                                   int* __restrict__ ntiles64,
                                                   int* __restrict__ tnode16,
                                                   int* __restrict__ tstart16,
                                                   int* __restrict__ tend16,
                                                   int* __restrict__ ntiles16) {
  __shared__ int c[NN_], o[NN_], cur[NN_];
  int t = threadIdx.x;
  if (t < NN_) c[t] = 0;
  __syncthreads();
  for (int p = t; p < P_; p += 256) atomicAdd(&c[node[p]], 1);
  __syncthreads();
  if (t == 0) {
    int s = 0;
    for (int n = 0; n < NN_; n++) { o[n] = s; cur[n] = s; s += c[n]; }
    int i64 = 0, i16 = 0;
    for (int n = 0; n < NN_; n++) {
      int e = o[n] + c[n];
      for (int m0 = o[n]; m0 < e; m0 += 64) {
        tnode64[i64] = n; tstart64[i64] = m0; tend64[i64] = e; i64++;
      }
      for (int m0 = o[n]; m0 < e; m0 += 16) {
        tnode16[i16] = n; tstart16[i16] = m0; tend16[i16] = e; i16++;
      }
    }
    ntiles64[0] = i64;
    ntiles16[0] = i16;
  }
  __syncthreads();
  if (t < NN_) { cnts[t] = c[t]; offs[t] = o[t]; }
  for (int p = t; p < P_; p += 256) {
    int r = atomicAdd(&cur[node[p]], 1);
    order[r] = p;
    invord[p] = r;
  }
}

// ---------------- LN with per-node affine -> split bf16 hi/lo, SORTED -------
__global__ __launch_bounds__(256) void ln_affine(const float* __restrict__ h,
                                                 const float* __restrict__ g,
                                                 const float* __restrict__ b,
                                                 const int* __restrict__ node,
                                                 const int* __restrict__ order,
                                                 unsigned short* __restrict__ xh,
                                                 unsigned short* __restrict__ xl) {
  int sp = blockIdx.x * 4 + (threadIdx.x >> 6);
  int lane = threadIdx.x & 63;
  int p = order[sp];
  int n = node[p];
  float4 v = *(const float4*)&h[(size_t)p * D_ + lane * 4];
  float s = v.x + v.y + v.z + v.w;
#pragma unroll
  for (int off = 32; off > 0; off >>= 1) s += __shfl_xor(s, off, 64);
  float mean = s * (1.0f / D_);
  float4 d = make_float4(v.x - mean, v.y - mean, v.z - mean, v.w - mean);
  float vr = d.x * d.x + d.y * d.y + d.z * d.z + d.w * d.w;
#pragma unroll
  for (int off = 32; off > 0; off >>= 1) vr += __shfl_xor(vr, off, 64);
  float inv = 1.0f / sqrtf(vr * (1.0f / D_) + 1e-5f);
  float4 gg = *(const float4*)&g[n * D_ + lane * 4];
  float4 bb = *(const float4*)&b[n * D_ + lane * 4];
  float o[4];
  o[0] = d.x * inv * gg.x + bb.x;
  o[1] = d.y * inv * gg.y + bb.y;
  o[2] = d.z * inv * gg.z + bb.z;
  o[3] = d.w * inv * gg.w + bb.w;
  ushort4 oh, ol;
  split2(o[0], oh.x, ol.x);
  split2(o[1], oh.y, ol.y);
  split2(o[2], oh.z, ol.z);
  split2(o[3], oh.w, ol.w);
  *(ushort4*)&xh[(size_t)sp * D_ + lane * 4] = oh;
  *(ushort4*)&xl[(size_t)sp * D_ + lane * 4] = ol;
}

// ---------------- weight prep: W[n][k][c] f32 -> Wt hi/lo [n][c][k] bf16 ----
template <int K, int C>
__global__ __launch_bounds__(256) void wprep(const float* __restrict__ W,
                                             unsigned short* __restrict__ th,
                                             unsigned short* __restrict__ tl) {
  __shared__ float ld[32][33];
  int n = blockIdx.z;
  int k0 = blockIdx.x * 32, c0 = blockIdx.y * 32;
  int tx = threadIdx.x & 31, ty = threadIdx.x >> 5;  // 32 x 8
  const float* Wn = W + (size_t)n * K * C;
#pragma unroll
  for (int i = 0; i < 32; i += 8)
    ld[i + ty][tx] = Wn[(size_t)(k0 + i + ty) * C + c0 + tx];
  __syncthreads();
#pragma unroll
  for (int i = 0; i < 32; i += 8) {
    float v = ld[tx][i + ty];
    unsigned short hh, ll;
    split2(v, hh, ll);
    size_t off = ((size_t)n * C + c0 + i + ty) * K + k0 + tx;
    th[off] = hh;
    tl[off] = ll;
  }
}

// ---------------- grouped linear via MFMA (bf16x3), B via LDS DMA -----------
// Block = 256 thr = 4 waves; wave wv owns a 16x16 output tile: rows = the
// 16-row node-tile, cols = jb + wv*16. KC=64 K-chunks (2 MFMA K-steps),
// B double-buffered in LDS via global_load_lds (latency hidden in the DMA
// queue, drained by the end-of-chunk barrier AFTER compute — R0's schedule).
// LDS chunk layout [step][col][granule]: granule gs of col c holds element
// e = gs ^ (c&7), e = half*4+kg (hi/lo interleaved in one 128B row -> the
// per-instruction read spreads across both bank halves). Staging pre-swizzles
// the per-lane GLOBAL source; LDS dest stays linear (m173 pattern).
// A (x hi/lo) per-lane global 16B loads, identical across waves (L1
// broadcast), ping-ponged one chunk ahead in registers.
// acc = xh*Wh + xh*Wl + xl*Wh (3 chains, ~fp32-grade).
// C/D: col=lane&15, row=(lane>>4)*4+reg [m89-verified].
template <int DIN, int DOUT, int ACT, int RESID, int SPLITOUT>
__global__ __launch_bounds__(256) void gmfma(
    const unsigned short* __restrict__ xh, const unsigned short* __restrict__ xl,
    const unsigned short* __restrict__ wth, const unsigned short* __restrict__ wtl,
    const float* __restrict__ bias, float* __restrict__ outf,
    unsigned short* __restrict__ outh, unsigned short* __restrict__ outl,
    const int* __restrict__ order, const int* __restrict__ tnode,
    const int* __restrict__ tstart, const int* __restrict__ tend,
    const int* __restrict__ ntiles) {
  constexpr int NCH = DIN / 64;
  __shared__ unsigned short ws[2][2][64][64];  // 32 KB: [dbuf][step][col][gs*8]

  int gx = gridDim.x;
  int bid = blockIdx.x;
  int ti = (bid & 7) * (gx >> 3) + (bid >> 3);  // bijective XCD swizzle (gx%8==0)
  if (ti >= ntiles[0]) return;
  int n = tnode[ti];
  int s0 = tstart[ti];
  int rows = tend[ti] - s0;
  if (rows <= 0) return;
  if (rows > 16) rows = 16;

  int tid = threadIdx.x;
  int wv = tid >> 6;
  int lane = tid & 63;
  int r16 = lane & 15;
  int kg = lane >> 4;  // 0..3
  int jb = blockIdx.y * 64;

  // ---- B staging: 16 DMA insts/block/chunk (4 per wave), j = wv*4+jj ----
  const unsigned short* wsrc[4];
  int sj[4], c0j[4];
#pragma unroll
  for (int jj = 0; jj < 4; jj++) {
    int j = wv * 4 + jj;
    int s = j >> 3;          // K-step within chunk
    int c0 = (j & 7) * 8;    // col group base
    int c = c0 + (lane >> 3);
    int e = (lane & 7) ^ (c & 7);  // element stored at this lane's granule
    wsrc[jj] = ((e & 4) ? wtl : wth) +
               ((size_t)(n * DOUT + jb + c)) * DIN + s * 32 + (e & 3) * 8;
    sj[jj] = s;
    c0j[jj] = c0;
  }
  auto stage = [&](int buf, int kbase) {
#pragma unroll
    for (int jj = 0; jj < 4; jj++) {
      __builtin_amdgcn_global_load_lds(
          (const __attribute__((address_space(1))) unsigned int*)(wsrc[jj] + kbase),
          (__attribute__((address_space(3))) unsigned int*)&ws[buf][sj[jj]][c0j[jj]][0],
          16, 0, 0);
    }
  };

  // ---- A pointers (per-lane; identical across 4 waves -> L1 broadcast) ----
  const unsigned short* pah = xh + (size_t)(s0 + r16) * DIN + kg * 8;
  const unsigned short* pal = xl + (size_t)(s0 + r16) * DIN + kg * 8;

  short8v ah[2], al[2], nh[2], nl[2];
  auto afetch = [&](int kbase, short8v (&h_)[2], short8v (&l_)[2]) {
#pragma unroll
    for (int s = 0; s < 2; s++) {
      h_[s] = *(const short8v*)(pah + kbase + s * 32);
      l_[s] = *(const short8v*)(pal + kbase + s * 32);
    }
  };

  f32x4 acc0 = {0.f, 0.f, 0.f, 0.f};
  f32x4 acc1 = acc0, acc2 = acc0;
  int lcol = wv * 16 + r16;               // my LDS col row
  int ghi_ = (kg ^ (r16 & 7)) * 8;        // hi granule offset (shorts)
  int glo_ = ((4 + kg) ^ (r16 & 7)) * 8;  // lo granule offset

  stage(0, 0);
  afetch(0, ah, al);
  __syncthreads();  // drains vmcnt (incl. DMA) before first use

  for (int ch = 0; ch < NCH; ch++) {
    int cur = ch & 1;
    if (ch + 1 < NCH) {
      stage(cur ^ 1, (ch + 1) * 64);       // lands before next-iter barrier
      afetch((ch + 1) * 64, nh, nl);       // reg prefetch
    }
#pragma unroll
    for (int s = 0; s < 2; s++) {
      short8v bh = *(const short8v*)&ws[cur][s][lcol][ghi_];
      short8v bl = *(const short8v*)&ws[cur][s][lcol][glo_];
      acc0 = __builtin_amdgcn_mfma_f32_16x16x32_bf16(ah[s], bh, acc0, 0, 0, 0);
      acc1 = __builtin_amdgcn_mfma_f32_16x16x32_bf16(ah[s], bl, acc1, 0, 0, 0);
      acc2 = __builtin_amdgcn_mfma_f32_16x16x32_bf16(al[s], bh, acc2, 0, 0, 0);
    }
    __syncthreads();  // all waves done with ws[cur]; drains next-chunk DMA
    if (ch + 1 < NCH) {
#pragma unroll
      for (int s = 0; s < 2; s++) { ah[s] = nh[s]; al[s] = nl[s]; }
    }
  }

  // ---- epilogue ----
  int jcol = jb + wv * 16;
  float bv = bias[(size_t)n * DOUT + jcol + r16];
#pragma unroll
  for (int rg = 0; rg < 4; rg++) {
    int r = kg * 4 + rg;
    if (r >= rows) continue;
    float v = acc0[rg] + acc1[rg] + acc2[rg] + bv;
    if (ACT) v = gelu_tanh(v);
    if (SPLITOUT) {
      size_t off = (size_t)(s0 + r) * DOUT + jcol + r16;
      unsigned short hh, ll;
      split2(v, hh, ll);
      outh[off] = hh;
      outl[off] = ll;
    } else if (RESID) {
      int pp = order[s0 + r];
      float* op = outf + (size_t)pp * DOUT + jcol + r16;
      *op += v;
    } else {
      outf[(size_t)(s0 + r) * DOUT + jcol + r16] = v;
    }
  }
}

// ---------------- grouped linear (R0 vector version, verbatim) --------------
template <int DIN, int DOUT, int JT, int ACT, int RESID, int PER_NODE, int KSPLIT, int XMODE>
__global__ __launch_bounds__(256) void glin(const float* __restrict__ x,
                                            const float* __restrict__ W,
                                            const float* __restrict__ bias,
                                            float* __restrict__ out,
                                            float* __restrict__ pbuf,
                                            const float* __restrict__ xaux,
                                            const int* __restrict__ order,
                                            const int* __restrict__ invord,
                                            const int* __restrict__ tnode,
                                            const int* __restrict__ tstart,
                                            const int* __restrict__ tend,
                                            const int* __restrict__ ntiles) {
  constexpr int KC = 32, STX = 68;
  constexpr int CPT = JT / 16;
  constexpr int HALF = 64;
  constexpr int KLEN = DIN / KSPLIT;
  constexpr int NCH = KLEN / KC;
  constexpr int LPR = JT / 4;
  constexpr int RPI = 64 / LPR;

  int ti = blockIdx.x;
  int n, s0, s1;
  if (PER_NODE) {
    if (ti >= ntiles[0]) return;
    n = tnode[ti]; s0 = tstart[ti]; s1 = tend[ti];
  } else {
    n = 0; s0 = ti * 64; s1 = P_;
  }
  int jbase = blockIdx.y * JT;
  int kz = (KSPLIT > 1) ? blockIdx.z : 0;
  int k0 = kz * KLEN;
  int rows = s1 - s0; if (rows > 64) rows = 64;

  __shared__ float xs[2][KC][STX];
  __shared__ float ws[2][KC][JT];

  int tid = threadIdx.x;
  const float* Wn = W + (size_t)n * DIN * DOUT + jbase;

  int xrow = tid >> 2, xq = tid & 3;
  bool xvalid = xrow < rows;
  const float* xptr = x + (size_t)(s0 + (xvalid ? xrow : 0)) * DIN + k0 + xq * 4;
  const float* aptr = nullptr;
  if (XMODE == 1) {
    int pr = xvalid ? invord[s0 + xrow] : 0;
    aptr = xaux + (size_t)pr * DIN + k0 + xq * 4;
  }

  float4 xr0, xr1;
  auto xfetch = [&](int kc) {
    if (xvalid) {
      xr0 = *(const float4*)(xptr + kc);
      xr1 = *(const float4*)(xptr + kc + 16);
      if (XMODE == 1) {
        float4 p0 = *(const float4*)(aptr + kc);
        float4 p1 = *(const float4*)(aptr + kc + 16);
        xr0.x += p0.x; xr0.y += p0.y; xr0.z += p0.z; xr0.w += p0.w;
        xr1.x += p1.x; xr1.y += p1.y; xr1.z += p1.z; xr1.w += p1.w;
      }
    } else {
      xr0 = make_float4(0.f, 0.f, 0.f, 0.f);
      xr1 = make_float4(0.f, 0.f, 0.f, 0.f);
    }
  };
  auto xstage = [&](int buf) {
    xs[buf][xq * 4 + 0][xrow] = xr0.x;
    xs[buf][xq * 4 + 1][xrow] = xr0.y;
    xs[buf][xq * 4 + 2][xrow] = xr0.z;
    xs[buf][xq * 4 + 3][xrow] = xr0.w;
    xs[buf][xq * 4 + 16][xrow] = xr1.x;
    xs[buf][xq * 4 + 17][xrow] = xr1.y;
    xs[buf][xq * 4 + 18][xrow] = xr1.z;
    xs[buf][xq * 4 + 19][xrow] = xr1.w;
  };
  int wvw = tid >> 6, lane = tid & 63;
  int wlr = lane / LPR;
  int wlc = (lane % LPR) * 4;
  auto wfetch = [&](int buf, int kc) {
#pragma unroll
    for (int i = 0; i < 8 / RPI; i++) {
      int kr = wvw * 8 + i * RPI;
      const float* g = &Wn[(size_t)(k0 + kc + kr + wlr) * DOUT + wlc];
      __builtin_amdgcn_global_load_lds(
          (const __attribute__((address_space(1))) unsigned int*)g,
          (__attribute__((address_space(3))) unsigned int*)&ws[buf][kr][0],
          16, 0, 0);
    }
  };

  wfetch(0, 0);
  xfetch(0);
  xstage(0);
  __syncthreads();

  int r4 = (tid >> 4) * 4;
  int jc4 = (tid & 15) * 4;
  float acc[4][CPT];
#pragma unroll
  for (int r = 0; r < 4; r++)
#pragma unroll
    for (int cc = 0; cc < CPT; cc++) acc[r][cc] = 0.f;

  for (int c = 0; c < NCH; c++) {
    int cur = c & 1;
    if (c + 1 < NCH) {
      wfetch(cur ^ 1, (c + 1) * KC);
      xfetch((c + 1) * KC);
    }
#pragma unroll 8
    for (int k = 0; k < KC; k++) {
      float4 a = *(const float4*)&xs[cur][k][r4];
      float av[4] = {a.x, a.y, a.z, a.w};
      float bv[CPT];
      float4 b0 = *(const float4*)&ws[cur][k][jc4];
      bv[0] = b0.x; bv[1] = b0.y; bv[2] = b0.z; bv[3] = b0.w;
      if (CPT == 8) {
        float4 b1 = *(const float4*)&ws[cur][k][jc4 + HALF];
        bv[4] = b1.x; bv[5] = b1.y; bv[6] = b1.z; bv[7] = b1.w;
      }
#pragma unroll
      for (int r = 0; r < 4; r++)
#pragma unroll
        for (int cc = 0; cc < CPT; cc++) acc[r][cc] += av[r] * bv[cc];
    }
    if (c + 1 < NCH) xstage(cur ^ 1);
    __syncthreads();
  }

  bool main_part = (KSPLIT == 1) || (kz == 0);
  float bbv[CPT];
#pragma unroll
  for (int cc = 0; cc < 4; cc++) bbv[cc] = bias[n * DOUT + jbase + jc4 + cc];
  if (CPT == 8) {
#pragma unroll
    for (int cc = 0; cc < 4; cc++) bbv[4 + cc] = bias[n * DOUT + jbase + jc4 + HALF + cc];
  }

#pragma unroll
  for (int r = 0; r < 4; r++) {
    int lr = r4 + r;
    if (lr >= rows) continue;
    float v[CPT];
    if (main_part) {
#pragma unroll
      for (int cc = 0; cc < CPT; cc++) {
        v[cc] = acc[r][cc] + bbv[cc];
        if (ACT == 1) v[cc] = gelu_tanh(v[cc]);
      }
      if (RESID) {
        int pp = PER_NODE ? order[s0 + lr] : (s0 + lr);
        float* op = &out[(size_t)pp * DOUT + jbase + jc4];
        {
          float4 old = *(const float4*)op;
          *(float4*)op = make_float4(v[0] + old.x, v[1] + old.y, v[2] + old.z, v[3] + old.w);
        }
        if (CPT == 8) {
          float4 old = *(const float4*)(op + HALF);
          *(float4*)(op + HALF) =
              make_float4(v[4] + old.x, v[5] + old.y, v[6] + old.z, v[7] + old.w);
        }
      } else {
        float* op = &out[(size_t)(s0 + lr) * DOUT + jbase + jc4];
        *(float4*)op = make_float4(v[0], v[1], v[2], v[3]);
        if (CPT == 8)
          *(float4*)(op + HALF) = make_float4(v[4], v[5], v[6], v[7]);
      }
    } else {
      float* op = &pbuf[(size_t)(s0 + lr) * DOUT + jbase + jc4];
      *(float4*)op = make_float4(acc[r][0], acc[r][1], acc[r][2], acc[r][3]);
      if (CPT == 8)
        *(float4*)(op + HALF) = make_float4(acc[r][4], acc[r][5], acc[r][6], acc[r][7]);
    }
  }
}

// ---------------- same-node attention, flash-style, sorted qkv/ao ----------
#define ATS 36
__global__ __launch_bounds__(256) void attn_kernel(const float* __restrict__ qkv,
                                                   const int* __restrict__ node,
                                                   const int* __restrict__ order,
                                                   const int* __restrict__ offs,
                                                   const int* __restrict__ cnts,
                                                   float* __restrict__ ao) {
  __shared__ float qs[32 * ATS];
  __shared__ float kts[32 * ATS];
  __shared__ float vs[32 * ATS];
  __shared__ float ps[32 * ATS];
  __shared__ int glo[32], ghi[32];

  int t = threadIdx.x;
  int r = t >> 3;
  int j4 = (t & 7) * 4;
  int r0 = blockIdx.x * 32;
  int hd = blockIdx.y;

  if (t < 32) {
    int n = node[order[r0 + t]];
    glo[t] = offs[n];
    ghi[t] = offs[n] + cnts[n];
  }
  __syncthreads();

  {
    const float* qp = &qkv[(size_t)(r0 + r) * 768 + hd * 32 + j4];
    float4 q4 = *(const float4*)qp;
    q4.x *= INV_SQRT_DH; q4.y *= INV_SQRT_DH; q4.z *= INV_SQRT_DH; q4.w *= INV_SQRT_DH;
    *(float4*)&qs[r * ATS + j4] = q4;
  }

  int lo = glo[0];
  int hi = ghi[31];
  int myglo = glo[r], myghi = ghi[r];

  float4 o4 = {0.f, 0.f, 0.f, 0.f};
  float mrow = -1e30f, lrow = 0.f;

  for (int kt = lo; kt < hi; kt += 32) {
    int sj = kt + r;
    float4 k4 = {0.f, 0.f, 0.f, 0.f}, v4 = {0.f, 0.f, 0.f, 0.f};
    if (sj < hi) {
      const float* kp = &qkv[(size_t)sj * 768 + 256 + hd * 32 + j4];
      k4 = *(const float4*)kp;
      v4 = *(const float4*)(kp + 256);
    }
    __syncthreads();
    kts[(j4 + 0) * ATS + r] = k4.x;
    kts[(j4 + 1) * ATS + r] = k4.y;
    kts[(j4 + 2) * ATS + r] = k4.z;
    kts[(j4 + 3) * ATS + r] = k4.w;
    *(float4*)&vs[r * ATS + j4] = v4;
    __syncthreads();

    float s0 = 0.f, s1 = 0.f, s2 = 0.f, s3 = 0.f;
#pragma unroll 8
    for (int d = 0; d < 32; d++) {
      float qv = qs[r * ATS + d];
      float4 kv = *(const float4*)&kts[d * ATS + j4];
      s0 += qv * kv.x; s1 += qv * kv.y; s2 += qv * kv.z; s3 += qv * kv.w;
    }
    int c0 = kt + j4;
    if (c0 + 0 < myglo || c0 + 0 >= myghi) s0 = -1e30f;
    if (c0 + 1 < myglo || c0 + 1 >= myghi) s1 = -1e30f;
    if (c0 + 2 < myglo || c0 + 2 >= myghi) s2 = -1e30f;
    if (c0 + 3 < myglo || c0 + 3 >= myghi) s3 = -1e30f;

    float mx = fmaxf(fmaxf(s0, s1), fmaxf(s2, s3));
#pragma unroll
    for (int off = 4; off > 0; off >>= 1) mx = fmaxf(mx, __shfl_xor(mx, off, 8));
    float mnew = fmaxf(mrow, mx);
    float alpha = __expf(mrow - mnew);
    float p0 = __expf(s0 - mnew), p1 = __expf(s1 - mnew);
    float p2 = __expf(s2 - mnew), p3 = __expf(s3 - mnew);
    float ls = p0 + p1 + p2 + p3;
#pragma unroll
    for (int off = 4; off > 0; off >>= 1) ls += __shfl_xor(ls, off, 8);
    lrow = lrow * alpha + ls;
    mrow = mnew;
    o4.x *= alpha; o4.y *= alpha; o4.z *= alpha; o4.w *= alpha;

    *(float4*)&ps[r * ATS + j4] = make_float4(p0, p1, p2, p3);
#pragma unroll 8
    for (int j = 0; j < 32; j++) {
      float pj = ps[r * ATS + j];
      float4 vv = *(const float4*)&vs[j * ATS + j4];
      o4.x += pj * vv.x; o4.y += pj * vv.y; o4.z += pj * vv.z; o4.w += pj * vv.w;
    }
  }

  float inv = 1.f / lrow;
  o4.x *= inv; o4.y *= inv; o4.z *= inv; o4.w *= inv;
  *(float4*)&ao[(size_t)(r0 + r) * D_ + hd * 32 + j4] = o4;
}

// ---------------- routing ----------------
__global__ __launch_bounds__(256) void route_kernel(float* __restrict__ h,
                                                    const float* __restrict__ dir_w,
                                                    const float* __restrict__ dir_b,
                                                    const float* __restrict__ at,
                                                    const float* __restrict__ mag_w,
                                                    const float* __restrict__ mag_b,
                                                    const float* __restrict__ delta,
                                                    int* __restrict__ node) {
  int p = blockIdx.x, t = threadIdx.x;
  __shared__ float hs[D_];
  __shared__ float dpart[8][AD_];
  __shared__ float dirs[AD_];
  __shared__ float scs[NN_];
  __shared__ float red[4];
  float hv = h[(size_t)p * D_ + t];
  hs[t] = hv;
  __syncthreads();

  int j = t & 31, seg = t >> 5;
  float part = 0.0f;
#pragma unroll 8
  for (int i = 0; i < 32; i++) {
    int ii = seg * 32 + i;
    part += hs[ii] * dir_w[ii * D_ + j];
  }
  dpart[seg][j] = part;
  __syncthreads();
  if (t < AD_) {
    float s = dir_b[t];
#pragma unroll
    for (int g = 0; g < 8; g++) s += dpart[g][t];
    dirs[t] = s;
  }
  __syncthreads();
  if (t < NN_) {
    float s = 0.0f;
#pragma unroll
    for (int a = 0; a < AD_; a++) s += dirs[a] * at[t * AD_ + a];
    scs[t] = s;
  }
  __syncthreads();
  if (t == 0) {
    float best = scs[0];
    int arg = 0;
    for (int nn = 1; nn < NN_; nn++)
      if (scs[nn] > best) { best = scs[nn]; arg = nn; }
    node[p] = arg;
  }
  float mag = block_sum256(hv * mag_w[t], red) + mag_b[0];
  float sig = 1.0f / (1.0f + __expf(-mag));
  h[(size_t)p * D_ + t] = hv + delta[(size_t)p * D_ + t] * sig;
}

// ---------------- final logits ----------------
__global__ __launch_bounds__(256) void out_kernel(const float* __restrict__ h,
                                                  const float* __restrict__ ow,
                                                  const float* __restrict__ ob,
                                                  float* __restrict__ out) {
  int p = blockIdx.x, t = threadIdx.x;
  __shared__ float hs[D_];
  __shared__ float part[8][NC_];
  hs[t] = h[(size_t)p * D_ + t];
  __syncthreads();
  int j = t & 31, seg = t >> 5;
  float s = 0.0f;
#pragma unroll 8
  for (int i = 0; i < 32; i++) {
    int ii = seg * 32 + i;
    s += hs[ii] * ow[ii * NC_ + j];
  }
  part[seg][j] = s;
  __syncthreads();
  if (t < NC_) {
    float r = ob[t];
#pragma unroll
    for (int g = 0; g < 8; g++) r += part[g][t];
    out[(size_t)p * NC_ + t] = r;
  }
}

extern "C" void kernel_launch(void* const* d_in, const int* in_sizes, int n_in,
                              void* d_out, int out_size, void* d_ws, size_t ws_size,
                              hipStream_t stream) {
  (void)in_sizes; (void)n_in; (void)out_size; (void)ws_size;
  const float* query_keys       = (const float*)d_in[0];
  const float* writer_keys      = (const float*)d_in[1];
  const float* key_proj_w       = (const float*)d_in[2];
  const float* key_proj_b       = (const float*)d_in[3];
  const float* class_embed      = (const float*)d_in[4];
  const float* role_embed       = (const float*)d_in[5];
  const float* start_node_embed = (const float*)d_in[6];
  const float* input_ln_g       = (const float*)d_in[7];
  const float* input_ln_b       = (const float*)d_in[8];
  const float* ln1_g            = (const float*)d_in[9];
  const float* ln1_b            = (const float*)d_in[10];
  const float* wqkv             = (const float*)d_in[11];
  const float* bqkv             = (const float*)d_in[12];
  const float* wo               = (const float*)d_in[13];
  const float* bo               = (const float*)d_in[14];
  const float* ln2_g            = (const float*)d_in[15];
  const float* ln2_b            = (const float*)d_in[16];
  const float* w_fc1            = (const float*)d_in[17];
  const float* b_fc1            = (const float*)d_in[18];
  const float* w_fc2            = (const float*)d_in[19];
  const float* b_fc2            = (const float*)d_in[20];
  const float* delta_w          = (const float*)d_in[21];
  const float* delta_b          = (const float*)d_in[22];
  const float* dir_w            = (const float*)d_in[23];
  const float* dir_b            = (const float*)d_in[24];
  const float* mag_w            = (const float*)d_in[25];
  const float* mag_b            = (const float*)d_in[26];
  const float* out_w            = (const float*)d_in[27];
  const float* out_b            = (const float*)d_in[28];
  const float* address_table    = (const float*)d_in[29];
  const int* query_start_nodes  = (const int*)d_in[30];
  const int* writer_labels      = (const int*)d_in[31];
  const int* writer_start_nodes = (const int*)d_in[32];

  uintptr_t basep = (uintptr_t)d_ws;
  auto carve = [&](size_t bytes) {
    basep = (basep + 255) & ~(uintptr_t)255;
    void* r = (void*)basep;
    basep += bytes;
    return r;
  };
  float* h    = (float*)carve((size_t)P_ * D_ * 4);
  float* x    = (float*)carve((size_t)P_ * D_ * 4);             // ao f32 (sorted)
  float* buf1 = (float*)carve((size_t)P_ * 768 * 4);            // qkv f32; delta out
  unsigned short* xh  = (unsigned short*)carve((size_t)PS_ * D_ * 2);
  unsigned short* xl  = (unsigned short*)carve((size_t)PS_ * D_ * 2);
  unsigned short* ffh = (unsigned short*)carve((size_t)PS_ * DFF_ * 2);
  unsigned short* ffl = (unsigned short*)carve((size_t)PS_ * DFF_ * 2);
  unsigned short* wtqh = (unsigned short*)carve((size_t)NN_ * 768 * 256 * 2);
  unsigned short* wtql = (unsigned short*)carve((size_t)NN_ * 768 * 256 * 2);
  unsigned short* wt1h = (unsigned short*)carve((size_t)NN_ * 1024 * 256 * 2);
  unsigned short* wt1l = (unsigned short*)carve((size_t)NN_ * 1024 * 256 * 2);
  unsigned short* wt2h = (unsigned short*)carve((size_t)NN_ * 256 * 1024 * 2);
  unsigned short* wt2l = (unsigned short*)carve((size_t)NN_ * 256 * 1024 * 2);
  int* node   = (int*)carve(P_ * 4);
  int* order  = (int*)carve(P_ * 4);
  int* invord = (int*)carve(P_ * 4);
  int* offs   = (int*)carve(NN_ * 4);
  int* cnts   = (int*)carve(NN_ * 4);
  int* tnode64  = (int*)carve(MAXT_ * 4);
  int* tstart64 = (int*)carve(MAXT_ * 4);
  int* tend64   = (int*)carve(MAXT_ * 4);
  int* ntiles64 = (int*)carve(4);
  int* tnode16  = (int*)carve(MAXT2_ * 4);
  int* tstart16 = (int*)carve(MAXT2_ * 4);
  int* tend16   = (int*)carve(MAXT2_ * 4);
  int* ntiles16 = (int*)carve(4);

  // pad-row zeroing + one-time weight transpose+split (weights hop-invariant)
  padzero_kernel<<<1, 256, 0, stream>>>(xh, xl, ffh, ffl);
  wprep<256, 768><<<dim3(8, 24, NN_), 256, 0, stream>>>(wqkv, wtqh, wtql);
  wprep<256, 1024><<<dim3(8, 32, NN_), 256, 0, stream>>>(w_fc1, wt1h, wt1l);
  wprep<1024, 256><<<dim3(32, 8, NN_), 256, 0, stream>>>(w_fc2, wt2h, wt2l);

  encode_kernel<<<P_, 256, 0, stream>>>(query_keys, writer_keys, key_proj_w, key_proj_b,
                                        class_embed, role_embed, start_node_embed,
                                        input_ln_g, input_ln_b, query_start_nodes,
                                        writer_labels, writer_start_nodes, h, node);

  for (int hop = 0; hop < HOPS_; ++hop) {
    sort_kernel<<<1, 256, 0, stream>>>(node, order, invord, offs, cnts,
                                       tnode64, tstart64, tend64, ntiles64,
                                       tnode16, tstart16, tend16, ntiles16);
    ln_affine<<<P_ / 4, 256, 0, stream>>>(h, ln1_g, ln1_b, node, order, xh, xl);
    // qkv: [256 -> 768] MFMA, 12 col panels of 64, sorted f32 out
    gmfma<256, 768, 0, 0, 0><<<dim3(MAXT2_, 12), 256, 0, stream>>>(
        xh, xl, wtqh, wtql, bqkv, buf1, nullptr, nullptr, order,
        tnode16, tstart16, tend16, ntiles16);
    attn_kernel<<<dim3(P_ / 32, NH_), 256, 0, stream>>>(buf1, node, order, offs,
                                                        cnts, x /*ao, sorted*/);
    // wo: [256 -> 256] vector glin (R0), residual into h
    glin<256, 256, 64, 0, 1, 1, 1, 0><<<dim3(MAXT_, 4), 256, 0, stream>>>(
        x, wo, bo, h, nullptr, nullptr, order, invord, tnode64, tstart64, tend64,
        ntiles64);
    ln_affine<<<P_ / 4, 256, 0, stream>>>(h, ln2_g, ln2_b, node, order, xh, xl);
    // fc1: [256 -> 1024] MFMA + GELU, split bf16 out
    gmfma<256, 1024, 1, 0, 1><<<dim3(MAXT2_, 16), 256, 0, stream>>>(
        xh, xl, wt1h, wt1l, b_fc1, nullptr, ffh, ffl, order,
        tnode16, tstart16, tend16, ntiles16);
    // fc2: [1024 -> 256] MFMA, residual into h (packet space)
    gmfma<1024, 256, 0, 1, 0><<<dim3(MAXT2_, 4), 256, 0, stream>>>(
        ffh, ffl, wt2h, wt2l, b_fc2, h, nullptr, nullptr, order,
        tnode16, tstart16, tend16, ntiles16);
    // delta = h @ delta_w + delta_b (dense packet space, vector glin)
    glin<256, 256, 64, 0, 0, 0, 1, 0><<<dim3(P_ / 64, 4), 256, 0, stream>>>(
        h, delta_w, delta_b, buf1 /*delta out*/, nullptr, nullptr, order, invord,
        tnode64, tstart64, tend64, ntiles64);
    route_kernel<<<P_, 256, 0, stream>>>(h, dir_w, dir_b, address_table,
                                         mag_w, mag_b, buf1, node);
  }

  out_kernel<<<P_, 256, 0, stream>>>(h, out_w, out_b, (float*)d_out);
}

// Round 8
// 871.503 us; speedup vs baseline: 1.7599x; 1.0682x over previous
//
#include <hip/hip_runtime.h>
#include <math.h>

// Problem constants
#define B_    512
#define W_    4
#define KD_   64
#define NC_   32
#define D_    256
#define NN_   16
#define NH_   8
#define AD_   32
#define HOPS_ 4
#define DH_   32
#define DFF_  1024
#define P_    2560
#define BW_   2048   // B*W
#define MAXT2_ 176   // worst-case 16-row M-tiles: P/16 + (NN-1) = 175 -> 176 (%8==0)
#define PS_   (P_ + 16)  // padded row stride

#define INV_SQRT_DH 0.17677669529663687f  // 1/sqrt(32)

typedef __attribute__((ext_vector_type(8))) short short8v;
typedef __attribute__((ext_vector_type(4))) float f32x4;

// ---------------- bf16 split helpers ----------------
__device__ __forceinline__ unsigned short bf16_rne(float f) {
  unsigned u = __float_as_uint(f);
  unsigned r = (u + 0x7fffu + ((u >> 16) & 1u)) >> 16;
  return (unsigned short)r;
}
__device__ __forceinline__ void split2(float v, unsigned short& h, unsigned short& l) {
  unsigned short hb = bf16_rne(v);
  float hf = __uint_as_float(((unsigned)hb) << 16);
  h = hb;
  l = bf16_rne(v - hf);
}

// ---------------- block-wide sum over 256 threads ----------------
__device__ __forceinline__ float block_sum256(float v, float* red) {
#pragma unroll
  for (int off = 32; off > 0; off >>= 1) v += __shfl_xor(v, off, 64);
  int wid = threadIdx.x >> 6;
  if ((threadIdx.x & 63) == 0) red[wid] = v;
  __syncthreads();
  float s = red[0] + red[1] + red[2] + red[3];
  __syncthreads();
  return s;
}

__device__ __forceinline__ float gelu_tanh(float v) {
  float u = 0.7978845608028654f * (v + 0.044715f * v * v * v);
  return 0.5f * v * (1.0f + tanhf(u));
}

// ---------------- zero the +16 pad rows of the bf16 activation buffers ------
__global__ __launch_bounds__(256) void padzero_kernel(unsigned short* __restrict__ xh,
                                                      unsigned short* __restrict__ xl,
                                                      unsigned short* __restrict__ ffh,
                                                      unsigned short* __restrict__ ffl) {
  int t = threadIdx.x;
  for (int i = t; i < 16 * D_; i += 256) {
    xh[(size_t)P_ * D_ + i] = 0;
    xl[(size_t)P_ * D_ + i] = 0;
  }
  for (int i = t; i < 16 * DFF_; i += 256) {
    ffh[(size_t)P_ * DFF_ + i] = 0;
    ffl[(size_t)P_ * DFF_ + i] = 0;
  }
}

// ---------------- encode writers + queries -> h, node ----------------
__global__ __launch_bounds__(256) void encode_kernel(
    const float* __restrict__ query_keys, const float* __restrict__ writer_keys,
    const float* __restrict__ kpw, const float* __restrict__ kpb,
    const float* __restrict__ ce, const float* __restrict__ re,
    const float* __restrict__ sne, const float* __restrict__ ilg,
    const float* __restrict__ ilb, const int* __restrict__ qsn,
    const int* __restrict__ wl, const int* __restrict__ wsn,
    float* __restrict__ h, int* __restrict__ node) {
  int p = blockIdx.x, t = threadIdx.x;
  __shared__ float fk[KD_];
  __shared__ float red[4];
  const float* key;
  int lab = -1, sn, role;
  if (p < BW_) { key = writer_keys + (size_t)p * KD_; lab = wl[p]; sn = wsn[p]; role = 0; }
  else { int b = p - BW_; key = query_keys + (size_t)b * KD_; sn = qsn[b]; role = 1; }
  if (t < KD_) fk[t] = key[t];
  __syncthreads();

  float acc = kpb[t] + sne[sn * D_ + t] + re[role * D_ + t];
  if (lab >= 0) acc += ce[lab * D_ + t];
#pragma unroll 8
  for (int i = 0; i < KD_; i++) acc += fk[i] * kpw[i * D_ + t];

  float mean = block_sum256(acc, red) * (1.0f / D_);
  float d = acc - mean;
  float var = block_sum256(d * d, red) * (1.0f / D_);
  float xn = d * (1.0f / sqrtf(var + 1e-5f));

  float sw = 0.0f;
  if (t < KD_) sw = fk[t];
  else if (lab >= 0 && t < KD_ + NC_) sw = (t - KD_ == lab) ? 1.0f : 0.0f;

  h[(size_t)p * D_ + t] = xn * ilg[t] + ilb[t] + sw;
  if (t == 0) node[p] = sn;
}

// ---------------- group packets by node + 16-row tile worklist --------------
__global__ __launch_bounds__(256) void sort_kernel(const int* __restrict__ node,
                                                   int* __restrict__ order,
                                                   int* __restrict__ offs,
                                                   int* __restrict__ cnts,
                                                   int* __restrict__ tnode16,
                                                   int* __restrict__ tstart16,
                                                   int* __restrict__ tend16,
                                                   int* __restrict__ ntiles16) {
  __shared__ int c[NN_], o[NN_], cur[NN_];
  int t = threadIdx.x;
  if (t < NN_) c[t] = 0;
  __syncthreads();
  for (int p = t; p < P_; p += 256) atomicAdd(&c[node[p]], 1);
  __syncthreads();
  if (t == 0) {
    int s = 0;
    for (int n = 0; n < NN_; n++) { o[n] = s; cur[n] = s; s += c[n]; }
    int i16 = 0;
    for (int n = 0; n < NN_; n++) {
      int e = o[n] + c[n];
      for (int m0 = o[n]; m0 < e; m0 += 16) {
        tnode16[i16] = n; tstart16[i16] = m0; tend16[i16] = e; i16++;
      }
    }
    ntiles16[0] = i16;
  }
  __syncthreads();
  if (t < NN_) { cnts[t] = c[t]; offs[t] = o[t]; }
  for (int p = t; p < P_; p += 256) {
    int r = atomicAdd(&cur[node[p]], 1);
    order[r] = p;
  }
}

// ---------------- LN with per-node affine -> split bf16 hi/lo, SORTED -------
__global__ __launch_bounds__(256) void ln_affine(const float* __restrict__ h,
                                                 const float* __restrict__ g,
                                                 const float* __restrict__ b,
                                                 const int* __restrict__ node,
                                                 const int* __restrict__ order,
                                                 unsigned short* __restrict__ xh,
                                                 unsigned short* __restrict__ xl) {
  int sp = blockIdx.x * 4 + (threadIdx.x >> 6);
  int lane = threadIdx.x & 63;
  int p = order[sp];
  int n = node[p];
  float4 v = *(const float4*)&h[(size_t)p * D_ + lane * 4];
  float s = v.x + v.y + v.z + v.w;
#pragma unroll
  for (int off = 32; off > 0; off >>= 1) s += __shfl_xor(s, off, 64);
  float mean = s * (1.0f / D_);
  float4 d = make_float4(v.x - mean, v.y - mean, v.z - mean, v.w - mean);
  float vr = d.x * d.x + d.y * d.y + d.z * d.z + d.w * d.w;
#pragma unroll
  for (int off = 32; off > 0; off >>= 1) vr += __shfl_xor(vr, off, 64);
  float inv = 1.0f / sqrtf(vr * (1.0f / D_) + 1e-5f);
  float4 gg = *(const float4*)&g[n * D_ + lane * 4];
  float4 bb = *(const float4*)&b[n * D_ + lane * 4];
  float o[4];
  o[0] = d.x * inv * gg.x + bb.x;
  o[1] = d.y * inv * gg.y + bb.y;
  o[2] = d.z * inv * gg.z + bb.z;
  o[3] = d.w * inv * gg.w + bb.w;
  ushort4 oh, ol;
  split2(o[0], oh.x, ol.x);
  split2(o[1], oh.y, ol.y);
  split2(o[2], oh.z, ol.z);
  split2(o[3], oh.w, ol.w);
  *(ushort4*)&xh[(size_t)sp * D_ + lane * 4] = oh;
  *(ushort4*)&xl[(size_t)sp * D_ + lane * 4] = ol;
}

// ---------------- weight prep: W[n][k][c] f32 -> Wt hi/lo [n][c][k] bf16 ----
template <int K, int C>
__global__ __launch_bounds__(256) void wprep(const float* __restrict__ W,
                                             unsigned short* __restrict__ th,
                                             unsigned short* __restrict__ tl) {
  __shared__ float ld[32][33];
  int n = blockIdx.z;
  int k0 = blockIdx.x * 32, c0 = blockIdx.y * 32;
  int tx = threadIdx.x & 31, ty = threadIdx.x >> 5;  // 32 x 8
  const float* Wn = W + (size_t)n * K * C;
#pragma unroll
  for (int i = 0; i < 32; i += 8)
    ld[i + ty][tx] = Wn[(size_t)(k0 + i + ty) * C + c0 + tx];
  __syncthreads();
#pragma unroll
  for (int i = 0; i < 32; i += 8) {
    float v = ld[tx][i + ty];
    unsigned short hh, ll;
    split2(v, hh, ll);
    size_t off = ((size_t)n * C + c0 + i + ty) * K + k0 + tx;
    th[off] = hh;
    tl[off] = ll;
  }
}

// ---------------- grouped linear via MFMA (bf16x3), B via LDS DMA -----------
// See R6 notes: 4 waves x 16x16 tiles, KC=64 chunks, B double-buffered in LDS
// via global_load_lds with content swizzle (granule e = gs ^ (c&7)); A in
// registers (per-lane 16B, L1 broadcast), ping-ponged one chunk ahead.
// acc = xh*Wh + xh*Wl + xl*Wh. C/D: col=lane&15, row=(lane>>4)*4+reg.
// DENSE: n=0, s0=ti*16 (packet space, grid exact). HSPLIT: RESID result also
// written as split bf16 to houth/houtl (for the downstream dense gmfma).
template <int DIN, int DOUT, int ACT, int RESID, int SPLITOUT, int DENSE, int HSPLIT>
__global__ __launch_bounds__(256) void gmfma(
    const unsigned short* __restrict__ xh, const unsigned short* __restrict__ xl,
    const unsigned short* __restrict__ wth, const unsigned short* __restrict__ wtl,
    const float* __restrict__ bias, float* __restrict__ outf,
    unsigned short* __restrict__ outh, unsigned short* __restrict__ outl,
    unsigned short* __restrict__ houth, unsigned short* __restrict__ houtl,
    const int* __restrict__ order, const int* __restrict__ tnode,
    const int* __restrict__ tstart, const int* __restrict__ tend,
    const int* __restrict__ ntiles) {
  constexpr int NCH = DIN / 64;
  __shared__ unsigned short ws[2][2][64][64];  // 32 KB: [dbuf][step][col][gs*8]

  int gx = gridDim.x;
  int bid = blockIdx.x;
  int ti = (bid & 7) * (gx >> 3) + (bid >> 3);  // bijective XCD swizzle (gx%8==0)
  int n, s0, rows;
  if (DENSE) {
    n = 0;
    s0 = ti * 16;
    rows = 16;
  } else {
    if (ti >= ntiles[0]) return;
    n = tnode[ti];
    s0 = tstart[ti];
    rows = tend[ti] - s0;
    if (rows <= 0) return;
    if (rows > 16) rows = 16;
  }

  int tid = threadIdx.x;
  int wv = tid >> 6;
  int lane = tid & 63;
  int r16 = lane & 15;
  int kg = lane >> 4;  // 0..3
  int jb = blockIdx.y * 64;

  // ---- B staging: 16 DMA insts/block/chunk (4 per wave), j = wv*4+jj ----
  const unsigned short* wsrc[4];
  int sj[4], c0j[4];
#pragma unroll
  for (int jj = 0; jj < 4; jj++) {
    int j = wv * 4 + jj;
    int s = j >> 3;          // K-step within chunk
    int c0 = (j & 7) * 8;    // col group base
    int c = c0 + (lane >> 3);
    int e = (lane & 7) ^ (c & 7);  // element stored at this lane's granule
    wsrc[jj] = ((e & 4) ? wtl : wth) +
               ((size_t)(n * DOUT + jb + c)) * DIN + s * 32 + (e & 3) * 8;
    sj[jj] = s;
    c0j[jj] = c0;
  }
  auto stage = [&](int buf, int kbase) {
#pragma unroll
    for (int jj = 0; jj < 4; jj++) {
      __builtin_amdgcn_global_load_lds(
          (const __attribute__((address_space(1))) unsigned int*)(wsrc[jj] + kbase),
          (__attribute__((address_space(3))) unsigned int*)&ws[buf][sj[jj]][c0j[jj]][0],
          16, 0, 0);
    }
  };

  // ---- A pointers (per-lane; identical across 4 waves -> L1 broadcast) ----
  const unsigned short* pah = xh + (size_t)(s0 + r16) * DIN + kg * 8;
  const unsigned short* pal = xl + (size_t)(s0 + r16) * DIN + kg * 8;

  short8v ah[2], al[2], nh[2], nl[2];
  auto afetch = [&](int kbase, short8v (&h_)[2], short8v (&l_)[2]) {
#pragma unroll
    for (int s = 0; s < 2; s++) {
      h_[s] = *(const short8v*)(pah + kbase + s * 32);
      l_[s] = *(const short8v*)(pal + kbase + s * 32);
    }
  };

  f32x4 acc0 = {0.f, 0.f, 0.f, 0.f};
  f32x4 acc1 = acc0, acc2 = acc0;
  int lcol = wv * 16 + r16;               // my LDS col row
  int ghi_ = (kg ^ (r16 & 7)) * 8;        // hi granule offset (shorts)
  int glo_ = ((4 + kg) ^ (r16 & 7)) * 8;  // lo granule offset

  stage(0, 0);
  afetch(0, ah, al);
  __syncthreads();  // drains vmcnt (incl. DMA) before first use

  for (int ch = 0; ch < NCH; ch++) {
    int cur = ch & 1;
    if (ch + 1 < NCH) {
      stage(cur ^ 1, (ch + 1) * 64);       // lands before next-iter barrier
      afetch((ch + 1) * 64, nh, nl);       // reg prefetch
    }
#pragma unroll
    for (int s = 0; s < 2; s++) {
      short8v bh = *(const short8v*)&ws[cur][s][lcol][ghi_];
      short8v bl = *(const short8v*)&ws[cur][s][lcol][glo_];
      acc0 = __builtin_amdgcn_mfma_f32_16x16x32_bf16(ah[s], bh, acc0, 0, 0, 0);
      acc1 = __builtin_amdgcn_mfma_f32_16x16x32_bf16(ah[s], bl, acc1, 0, 0, 0);
      acc2 = __builtin_amdgcn_mfma_f32_16x16x32_bf16(al[s], bh, acc2, 0, 0, 0);
    }
    __syncthreads();  // all waves done with ws[cur]; drains next-chunk DMA
    if (ch + 1 < NCH) {
#pragma unroll
      for (int s = 0; s < 2; s++) { ah[s] = nh[s]; al[s] = nl[s]; }
    }
  }

  // ---- epilogue ----
  int jcol = jb + wv * 16;
  float bv = bias[(size_t)n * DOUT + jcol + r16];
#pragma unroll
  for (int rg = 0; rg < 4; rg++) {
    int r = kg * 4 + rg;
    if (r >= rows) continue;
    float v = acc0[rg] + acc1[rg] + acc2[rg] + bv;
    if (ACT) v = gelu_tanh(v);
    if (SPLITOUT) {
      size_t off = (size_t)(s0 + r) * DOUT + jcol + r16;
      unsigned short hh, ll;
      split2(v, hh, ll);
      outh[off] = hh;
      outl[off] = ll;
    } else if (RESID) {
      int pp = DENSE ? (s0 + r) : order[s0 + r];
      size_t oidx = (size_t)pp * DOUT + jcol + r16;
      float nv = outf[oidx] + v;
      outf[oidx] = nv;
      if (HSPLIT) {
        unsigned short hh, ll;
        split2(nv, hh, ll);
        houth[oidx] = hh;
        houtl[oidx] = ll;
      }
    } else {
      outf[(size_t)(s0 + r) * DOUT + jcol + r16] = v;
    }
  }
}

// ---------------- same-node attention, flash, double-buffered KV pipeline ---
// Per KV tile: next tile's global K/V loads issue BEFORE this tile's compute
// (latency hides under QK/softmax/PV), LDS tiles ping-pong, ONE barrier per
// tile (write buf^1 after compute, barrier, read next iter). Output written
// as split bf16 (feeds wo gmfma directly).
#define ATS 36
__global__ __launch_bounds__(256) void attn_kernel(const float* __restrict__ qkv,
                                                   const int* __restrict__ node,
                                                   const int* __restrict__ order,
                                                   const int* __restrict__ offs,
                                                   const int* __restrict__ cnts,
                                                   unsigned short* __restrict__ aoh,
                                                   unsigned short* __restrict__ aol) {
  __shared__ float qs[32 * ATS];
  __shared__ float kts[2][32 * ATS];
  __shared__ float vs[2][32 * ATS];
  __shared__ float ps[32 * ATS];
  __shared__ int glo[32], ghi[32];

  int t = threadIdx.x;
  int r = t >> 3;
  int j4 = (t & 7) * 4;
  int r0 = blockIdx.x * 32;
  int hd = blockIdx.y;

  if (t < 32) {
    int n = node[order[r0 + t]];
    glo[t] = offs[n];
    ghi[t] = offs[n] + cnts[n];
  }
  __syncthreads();

  {  // Q tile: sorted row r0+r, coalesced
    const float* qp = &qkv[(size_t)(r0 + r) * 768 + hd * 32 + j4];
    float4 q4 = *(const float4*)qp;
    q4.x *= INV_SQRT_DH; q4.y *= INV_SQRT_DH; q4.z *= INV_SQRT_DH; q4.w *= INV_SQRT_DH;
    *(float4*)&qs[r * ATS + j4] = q4;
  }

  int lo = glo[0];
  int hi = ghi[31];
  int myglo = glo[r], myghi = ghi[r];
  int nt = (hi - lo + 31) >> 5;

  {  // prologue: tile 0 -> buf 0
    int sj = lo + r;
    float4 k4 = {0.f, 0.f, 0.f, 0.f}, v4 = {0.f, 0.f, 0.f, 0.f};
    if (sj < hi) {
      const float* kp = &qkv[(size_t)sj * 768 + 256 + hd * 32 + j4];
      k4 = *(const float4*)kp;
      v4 = *(const float4*)(kp + 256);
    }
    kts[0][(j4 + 0) * ATS + r] = k4.x;
    kts[0][(j4 + 1) * ATS + r] = k4.y;
    kts[0][(j4 + 2) * ATS + r] = k4.z;
    kts[0][(j4 + 3) * ATS + r] = k4.w;
    *(float4*)&vs[0][r * ATS + j4] = v4;
  }
  __syncthreads();

  float4 o4 = {0.f, 0.f, 0.f, 0.f};
  float mrow = -1e30f, lrow = 0.f;

  for (int it = 0; it < nt; ++it) {
    int cb = it & 1;
    int kt = lo + it * 32;
    bool more = (it + 1 < nt);  // block-uniform

    // prefetch next tile's K/V into regs (overlaps with compute below)
    float4 kn = {0.f, 0.f, 0.f, 0.f}, vn = {0.f, 0.f, 0.f, 0.f};
    if (more) {
      int sj = kt + 32 + r;
      if (sj < hi) {
        const float* kp = &qkv[(size_t)sj * 768 + 256 + hd * 32 + j4];
        kn = *(const float4*)kp;
        vn = *(const float4*)(kp + 256);
      }
    }

    // ---- compute on buf cb ----
    float s0 = 0.f, s1 = 0.f, s2 = 0.f, s3 = 0.f;
#pragma unroll 8
    for (int d = 0; d < 32; d++) {
      float qv = qs[r * ATS + d];
      float4 kv = *(const float4*)&kts[cb][d * ATS + j4];
      s0 += qv * kv.x; s1 += qv * kv.y; s2 += qv * kv.z; s3 += qv * kv.w;
    }
    int c0 = kt + j4;
    if (c0 + 0 < myglo || c0 + 0 >= myghi) s0 = -1e30f;
    if (c0 + 1 < myglo || c0 + 1 >= myghi) s1 = -1e30f;
    if (c0 + 2 < myglo || c0 + 2 >= myghi) s2 = -1e30f;
    if (c0 + 3 < myglo || c0 + 3 >= myghi) s3 = -1e30f;

    float mx = fmaxf(fmaxf(s0, s1), fmaxf(s2, s3));
#pragma unroll
    for (int off = 4; off > 0; off >>= 1) mx = fmaxf(mx, __shfl_xor(mx, off, 8));
    float mnew = fmaxf(mrow, mx);
    float alpha = __expf(mrow - mnew);
    float p0 = __expf(s0 - mnew), p1 = __expf(s1 - mnew);
    float p2 = __expf(s2 - mnew), p3 = __expf(s3 - mnew);
    float ls = p0 + p1 + p2 + p3;
#pragma unroll
    for (int off = 4; off > 0; off >>= 1) ls += __shfl_xor(ls, off, 8);
    lrow = lrow * alpha + ls;
    mrow = mnew;
    o4.x *= alpha; o4.y *= alpha; o4.z *= alpha; o4.w *= alpha;

    *(float4*)&ps[r * ATS + j4] = make_float4(p0, p1, p2, p3);  // wave-coherent
#pragma unroll 8
    for (int j = 0; j < 32; j++) {
      float pj = ps[r * ATS + j];
      float4 vv = *(const float4*)&vs[cb][j * ATS + j4];
      o4.x += pj * vv.x; o4.y += pj * vv.y; o4.z += pj * vv.z; o4.w += pj * vv.w;
    }

    // ---- stage next tile into buf cb^1; single barrier per tile ----
    if (more) {
      kts[cb ^ 1][(j4 + 0) * ATS + r] = kn.x;
      kts[cb ^ 1][(j4 + 1) * ATS + r] = kn.y;
      kts[cb ^ 1][(j4 + 2) * ATS + r] = kn.z;
      kts[cb ^ 1][(j4 + 3) * ATS + r] = kn.w;
      *(float4*)&vs[cb ^ 1][r * ATS + j4] = vn;
      __syncthreads();
    }
  }

  float inv = 1.f / lrow;
  o4.x *= inv; o4.y *= inv; o4.z *= inv; o4.w *= inv;
  ushort4 oh4, ol4;
  split2(o4.x, oh4.x, ol4.x);
  split2(o4.y, oh4.y, ol4.y);
  split2(o4.z, oh4.z, ol4.z);
  split2(o4.w, oh4.w, ol4.w);
  size_t off = (size_t)(r0 + r) * D_ + hd * 32 + j4;
  *(ushort4*)&aoh[off] = oh4;
  *(ushort4*)&aol[off] = ol4;
}

// ---------------- routing ----------------
__global__ __launch_bounds__(256) void route_kernel(float* __restrict__ h,
                                                    const float* __restrict__ dir_w,
                                                    const float* __restrict__ dir_b,
                                                    const float* __restrict__ at,
                                                    const float* __restrict__ mag_w,
                                                    const float* __restrict__ mag_b,
                                                    const float* __restrict__ delta,
                                                    int* __restrict__ node) {
  int p = blockIdx.x, t = threadIdx.x;
  __shared__ float hs[D_];
  __shared__ float dpart[8][AD_];
  __shared__ float dirs[AD_];
  __shared__ float scs[NN_];
  __shared__ float red[4];
  float hv = h[(size_t)p * D_ + t];
  hs[t] = hv;
  __syncthreads();

  int j = t & 31, seg = t >> 5;
  float part = 0.0f;
#pragma unroll 8
  for (int i = 0; i < 32; i++) {
    int ii = seg * 32 + i;
    part += hs[ii] * dir_w[ii * D_ + j];
  }
  dpart[seg][j] = part;
  __syncthreads();
  if (t < AD_) {
    float s = dir_b[t];
#pragma unroll
    for (int g = 0; g < 8; g++) s += dpart[g][t];
    dirs[t] = s;
  }
  __syncthreads();
  if (t < NN_) {
    float s = 0.0f;
#pragma unroll
    for (int a = 0; a < AD_; a++) s += dirs[a] * at[t * AD_ + a];
    scs[t] = s;
  }
  __syncthreads();
  if (t == 0) {
    float best = scs[0];
    int arg = 0;
    for (int nn = 1; nn < NN_; nn++)
      if (scs[nn] > best) { best = scs[nn]; arg = nn; }
    node[p] = arg;
  }
  float mag = block_sum256(hv * mag_w[t], red) + mag_b[0];
  float sig = 1.0f / (1.0f + __expf(-mag));
  h[(size_t)p * D_ + t] = hv + delta[(size_t)p * D_ + t] * sig;
}

// ---------------- final logits ----------------
__global__ __launch_bounds__(256) void out_kernel(const float* __restrict__ h,
                                                  const float* __restrict__ ow,
                                                  const float* __restrict__ ob,
                                                  float* __restrict__ out) {
  int p = blockIdx.x, t = threadIdx.x;
  __shared__ float hs[D_];
  __shared__ float part[8][NC_];
  hs[t] = h[(size_t)p * D_ + t];
  __syncthreads();
  int j = t & 31, seg = t >> 5;
  float s = 0.0f;
#pragma unroll 8
  for (int i = 0; i < 32; i++) {
    int ii = seg * 32 + i;
    s += hs[ii] * ow[ii * NC_ + j];
  }
  part[seg][j] = s;
  __syncthreads();
  if (t < NC_) {
    float r = ob[t];
#pragma unroll
    for (int g = 0; g < 8; g++) r += part[g][t];
    out[(size_t)p * NC_ + t] = r;
  }
}

extern "C" void kernel_launch(void* const* d_in, const int* in_sizes, int n_in,
                              void* d_out, int out_size, void* d_ws, size_t ws_size,
                              hipStream_t stream) {
  (void)in_sizes; (void)n_in; (void)out_size; (void)ws_size;
  const float* query_keys       = (const float*)d_in[0];
  const float* writer_keys      = (const float*)d_in[1];
  const float* key_proj_w       = (const float*)d_in[2];
  const float* key_proj_b       = (const float*)d_in[3];
  const float* class_embed      = (const float*)d_in[4];
  const float* role_embed       = (const float*)d_in[5];
  const float* start_node_embed = (const float*)d_in[6];
  const float* input_ln_g       = (const float*)d_in[7];
  const float* input_ln_b       = (const float*)d_in[8];
  const float* ln1_g            = (const float*)d_in[9];
  const float* ln1_b            = (const float*)d_in[10];
  const float* wqkv             = (const float*)d_in[11];
  const float* bqkv             = (const float*)d_in[12];
  const float* wo               = (const float*)d_in[13];
  const float* bo               = (const float*)d_in[14];
  const float* ln2_g            = (const float*)d_in[15];
  const float* ln2_b            = (const float*)d_in[16];
  const float* w_fc1            = (const float*)d_in[17];
  const float* b_fc1            = (const float*)d_in[18];
  const float* w_fc2            = (const float*)d_in[19];
  const float* b_fc2            = (const float*)d_in[20];
  const float* delta_w          = (const float*)d_in[21];
  const float* delta_b          = (const float*)d_in[22];
  const float* dir_w            = (const float*)d_in[23];
  const float* dir_b            = (const float*)d_in[24];
  const float* mag_w            = (const float*)d_in[25];
  const float* mag_b            = (const float*)d_in[26];
  const float* out_w            = (const float*)d_in[27];
  const float* out_b            = (const float*)d_in[28];
  const float* address_table    = (const float*)d_in[29];
  const int* query_start_nodes  = (const int*)d_in[30];
  const int* writer_labels      = (const int*)d_in[31];
  const int* writer_start_nodes = (const int*)d_in[32];

  uintptr_t basep = (uintptr_t)d_ws;
  auto carve = [&](size_t bytes) {
    basep = (basep + 255) & ~(uintptr_t)255;
    void* r = (void*)basep;
    basep += bytes;
    return r;
  };
  float* h    = (float*)carve((size_t)P_ * D_ * 4);
  float* buf1 = (float*)carve((size_t)P_ * 768 * 4);   // qkv f32; delta out
  unsigned short* xh  = (unsigned short*)carve((size_t)PS_ * D_ * 2);  // ln out / ao
  unsigned short* xl  = (unsigned short*)carve((size_t)PS_ * D_ * 2);
  unsigned short* ffh = (unsigned short*)carve((size_t)PS_ * DFF_ * 2);
  unsigned short* ffl = (unsigned short*)carve((size_t)PS_ * DFF_ * 2);
  unsigned short* hh  = (unsigned short*)carve((size_t)P_ * D_ * 2);   // split h (fc2)
  unsigned short* hl  = (unsigned short*)carve((size_t)P_ * D_ * 2);
  unsigned short* wtqh = (unsigned short*)carve((size_t)NN_ * 768 * 256 * 2);
  unsigned short* wtql = (unsigned short*)carve((size_t)NN_ * 768 * 256 * 2);
  unsigned short* wt1h = (unsigned short*)carve((size_t)NN_ * 1024 * 256 * 2);
  unsigned short* wt1l = (unsigned short*)carve((size_t)NN_ * 1024 * 256 * 2);
  unsigned short* wt2h = (unsigned short*)carve((size_t)NN_ * 256 * 1024 * 2);
  unsigned short* wt2l = (unsigned short*)carve((size_t)NN_ * 256 * 1024 * 2);
  unsigned short* wtoh = (unsigned short*)carve((size_t)NN_ * 256 * 256 * 2);
  unsigned short* wtol = (unsigned short*)carve((size_t)NN_ * 256 * 256 * 2);
  unsigned short* dth  = (unsigned short*)carve((size_t)256 * 256 * 2);
  unsigned short* dtl  = (unsigned short*)carve((size_t)256 * 256 * 2);
  int* node   = (int*)carve(P_ * 4);
  int* order  = (int*)carve(P_ * 4);
  int* offs   = (int*)carve(NN_ * 4);
  int* cnts   = (int*)carve(NN_ * 4);
  int* tnode16  = (int*)carve(MAXT2_ * 4);
  int* tstart16 = (int*)carve(MAXT2_ * 4);
  int* tend16   = (int*)carve(MAXT2_ * 4);
  int* ntiles16 = (int*)carve(4);

  // pad-row zeroing + one-time weight transpose+split (weights hop-invariant)
  padzero_kernel<<<1, 256, 0, stream>>>(xh, xl, ffh, ffl);
  wprep<256, 768><<<dim3(8, 24, NN_), 256, 0, stream>>>(wqkv, wtqh, wtql);
  wprep<256, 1024><<<dim3(8, 32, NN_), 256, 0, stream>>>(w_fc1, wt1h, wt1l);
  wprep<1024, 256><<<dim3(32, 8, NN_), 256, 0, stream>>>(w_fc2, wt2h, wt2l);
  wprep<256, 256><<<dim3(8, 8, NN_), 256, 0, stream>>>(wo, wtoh, wtol);
  wprep<256, 256><<<dim3(8, 8, 1), 256, 0, stream>>>(delta_w, dth, dtl);

  encode_kernel<<<P_, 256, 0, stream>>>(query_keys, writer_keys, key_proj_w, key_proj_b,
                                        class_embed, role_embed, start_node_embed,
                                        input_ln_g, input_ln_b, query_start_nodes,
                                        writer_labels, writer_start_nodes, h, node);

  for (int hop = 0; hop < HOPS_; ++hop) {
    sort_kernel<<<1, 256, 0, stream>>>(node, order, offs, cnts,
                                       tnode16, tstart16, tend16, ntiles16);
    ln_affine<<<P_ / 4, 256, 0, stream>>>(h, ln1_g, ln1_b, node, order, xh, xl);
    // qkv: [256 -> 768] MFMA, 12 col panels of 64, sorted f32 out
    gmfma<256, 768, 0, 0, 0, 0, 0><<<dim3(MAXT2_, 12), 256, 0, stream>>>(
        xh, xl, wtqh, wtql, bqkv, buf1, nullptr, nullptr, nullptr, nullptr,
        order, tnode16, tstart16, tend16, ntiles16);
    // attn -> split bf16 ao (reuses xh/xl; qkv already consumed them)
    attn_kernel<<<dim3(P_ / 32, NH_), 256, 0, stream>>>(buf1, node, order, offs,
                                                        cnts, xh, xl);
    // wo: [256 -> 256] MFMA, residual into h (packet space)
    gmfma<256, 256, 0, 1, 0, 0, 0><<<dim3(MAXT2_, 4), 256, 0, stream>>>(
        xh, xl, wtoh, wtol, bo, h, nullptr, nullptr, nullptr, nullptr,
        order, tnode16, tstart16, tend16, ntiles16);
    ln_affine<<<P_ / 4, 256, 0, stream>>>(h, ln2_g, ln2_b, node, order, xh, xl);
    // fc1: [256 -> 1024] MFMA + GELU, split bf16 out
    gmfma<256, 1024, 1, 0, 1, 0, 0><<<dim3(MAXT2_, 16), 256, 0, stream>>>(
        xh, xl, wt1h, wt1l, b_fc1, nullptr, ffh, ffl, nullptr, nullptr,
        order, tnode16, tstart16, tend16, ntiles16);
    // fc2: [1024 -> 256] MFMA, residual into h + split(h_new) -> hh/hl
    gmfma<1024, 256, 0, 1, 0, 0, 1><<<dim3(MAXT2_, 4), 256, 0, stream>>>(
        ffh, ffl, wt2h, wt2l, b_fc2, h, nullptr, nullptr, hh, hl,
        order, tnode16, tstart16, tend16, ntiles16);
    // delta = h @ delta_w + delta_b (dense packet space MFMA)
    gmfma<256, 256, 0, 0, 0, 1, 0><<<dim3(P_ / 16, 4), 256, 0, stream>>>(
        hh, hl, dth, dtl, delta_b, buf1, nullptr, nullptr, nullptr, nullptr,
        order, tnode16, tstart16, tend16, ntiles16);
    route_kernel<<<P_, 256, 0, stream>>>(h, dir_w, dir_b, address_table,
                                         mag_w, mag_b, buf1, node);
  }

  out_kernel<<<P_, 256, 0, stream>>>(h, out_w, out_b, (float*)d_out);
}